// Round 6
// baseline (2756.108 us; speedup 1.0000x reference)
//
#include <hip/hip_runtime.h>
#include <stdint.h>

#define NN 50000
#define H 150
#define NE 400000
#define NG 64
#define NPASS 5
#define KB 480          // GRU GEMM K: [S0(160) | S1(160) | nodes(160)]
#define VC 640          // 40 col-tiles: v = cc*64 + g*16 + cl, c = cc*16+cl

typedef unsigned short u16;
typedef unsigned int u32;
typedef __attribute__((ext_vector_type(8))) short short8;
typedef __attribute__((ext_vector_type(4))) float float4v;
typedef __attribute__((ext_vector_type(4))) u32 uint4v;

// ---------------- helpers ----------------
__device__ __forceinline__ u16 f2bf_rn(float x) {
  union { float f; u32 u; } v; v.f = x;
  u32 r = v.u + 0x7fffu + ((v.u >> 16) & 1u);
  return (u16)(r >> 16);
}
__device__ __forceinline__ float bf2f(u16 h) {
  union { u32 u; float f; } v; v.u = ((u32)h) << 16;
  return v.f;
}
// packed node word: low16 = hi bf16, high16 = lo bf16; value = hi + lo
__device__ __forceinline__ u32 packf(float v) {
  u16 hi = f2bf_rn(v);
  u16 lo = f2bf_rn(v - bf2f(hi));
  return (u32)hi | ((u32)lo << 16);
}
__device__ __forceinline__ float upk(u32 u) {
  union { u32 u; float f; } a, b;
  a.u = u << 16; b.u = u & 0xffff0000u;
  return a.f + b.f;
}
// async global->LDS, 16B per lane; lds dest must be wave-uniform base
__device__ __forceinline__ void async16(const void* g, void* l) {
  __builtin_amdgcn_global_load_lds(
      (const __attribute__((address_space(1))) unsigned int*)(uintptr_t)g,
      (__attribute__((address_space(3))) unsigned int*)(uint32_t)(uintptr_t)l,
      16, 0, 0);
}

// ---------------- CSR build (key = node*2 + set) ----------------
__global__ void hist_kernel(const int* __restrict__ edges, int* __restrict__ cnt) {
  int id = blockIdx.x * 256 + threadIdx.x;
  if (id >= 2 * NE) return;
  int dst = edges[id * 2];
  int set = id / NE;
  atomicAdd(&cnt[dst * 2 + set], 1);
}

__global__ __launch_bounds__(1024) void scan1_kernel(const int* __restrict__ cnt,
                                                     int* __restrict__ rowptr,
                                                     int* __restrict__ bsum, int n) {
  __shared__ int sd[1024];
  int t = threadIdx.x;
  int idx = blockIdx.x * 1024 + t;
  int v = (idx < n) ? cnt[idx] : 0;
  sd[t] = v;
  __syncthreads();
  for (int off = 1; off < 1024; off <<= 1) {
    int add = (t >= off) ? sd[t - off] : 0;
    __syncthreads();
    sd[t] += add;
    __syncthreads();
  }
  if (idx < n) rowptr[idx] = sd[t] - v;     // block-local exclusive
  if (t == 1023) bsum[blockIdx.x] = sd[1023];
}

__global__ __launch_bounds__(128) void scan2_kernel(const int* __restrict__ bsum,
                                                    int* __restrict__ boff, int nb) {
  __shared__ int sd[128];
  int t = threadIdx.x;
  int v = (t < nb) ? bsum[t] : 0;
  sd[t] = v;
  __syncthreads();
  for (int off = 1; off < 128; off <<= 1) {
    int add = (t >= off) ? sd[t - off] : 0;
    __syncthreads();
    sd[t] += add;
    __syncthreads();
  }
  boff[t] = sd[t] - v;                       // exclusive; boff[nb] = total
}

__global__ void scan3_kernel(int* __restrict__ rowptr, const int* __restrict__ boff, int n) {
  int idx = blockIdx.x * 256 + threadIdx.x;
  if (idx < n) rowptr[idx] += boff[idx >> 10];
}

__global__ void total_kernel(int* __restrict__ rowptr, const int* __restrict__ boff, int n, int nb) {
  if (threadIdx.x == 0 && blockIdx.x == 0) rowptr[n] = boff[nb];
}

__global__ void copy_int_kernel(const int* __restrict__ a, int* __restrict__ b, int n) {
  int id = blockIdx.x * 256 + threadIdx.x;
  if (id < n) b[id] = a[id];
}

__global__ void fill_kernel(const int* __restrict__ edges, int* __restrict__ cursor,
                            u16* __restrict__ colbuf) {
  int id = blockIdx.x * 256 + threadIdx.x;
  if (id >= 2 * NE) return;
  int dst = edges[id * 2];
  int src = edges[id * 2 + 1];
  int set = id / NE;
  int pos = atomicAdd(&cursor[dst * 2 + set], 1);
  colbuf[pos] = (u16)src;
}

__global__ void bounds_kernel(const int* __restrict__ gids, int* __restrict__ gstart) {
  int g = threadIdx.x;
  if (g > NG) return;
  int lo = 0, hi = NN;
  while (lo < hi) { int m = (lo + hi) >> 1; if (gids[m] < g) lo = m + 1; else hi = m; }
  gstart[g] = lo;
}

// ---------------- one-time weight prep ----------------
// B'[v][k], v in [0,640): g=(v>>4)&3, c=(v>>6)*16+(v&15)
// k<160: (W_ihg @ W0)[c][k]      (g<3; g3=0)
// 160<=k<320: (W_ihg @ W1)[c][k-160]
// 320<=k<480: g0: w_hh[c][kk], g1: w_hh[150+c][kk], g3: w_hh[300+c][kk], g2: 0
__global__ void build_B_kernel(const float* __restrict__ wih, const float* __restrict__ whh,
                               const float* __restrict__ eW,
                               u16* __restrict__ Bh, u16* __restrict__ Bl) {
  int id = blockIdx.x * 256 + threadIdx.x;
  if (id >= VC * KB) return;
  int v = id / KB, k = id % KB;
  int g = (v >> 4) & 3, c = (v >> 6) * 16 + (v & 15);
  int seg = k / 160, kk = k % 160;
  float val = 0.f;
  if (c < H && kk < H) {
    if (seg < 2) {
      if (g < 3) {
        const float* wr = wih + (size_t)(g * H + c) * H;
        const float* wc = eW + (size_t)seg * H * H + kk;
        float acc = 0.f;
        for (int t = 0; t < H; t++) acc += wr[t] * wc[(size_t)t * H];
        val = acc;
      }
    } else {
      if (g == 0) val = whh[(size_t)c * H + kk];
      else if (g == 1) val = whh[(size_t)(H + c) * H + kk];
      else if (g == 3) val = whh[(size_t)(2 * H + c) * H + kk];
    }
  }
  u16 h = f2bf_rn(val);
  Bh[id] = h;
  Bl[id] = f2bf_rn(val - bf2f(h));
}

// coefs[0][g*160+c] = W_ihg @ b0 (deg0 coef), coefs[1] = W_ihg @ b1, coefs[2] = gate bias
__global__ void build_coef_kernel(const float* __restrict__ wih,
                                  const float* __restrict__ eb,
                                  const float* __restrict__ bih, const float* __restrict__ bhh,
                                  float* __restrict__ coefs) {
  int id = threadIdx.x + blockIdx.x * 256;
  if (id >= VC) return;
  int g = id / 160, c = id % 160;
  float u0 = 0.f, u1 = 0.f, bs = 0.f;
  if (c < H) {
    if (g < 3) {
      const float* wr = wih + (size_t)(g * H + c) * H;
      for (int t = 0; t < H; t++) { u0 += wr[t] * eb[t]; u1 += wr[t] * eb[H + t]; }
    }
    if (g == 0) bs = bih[c] + bhh[c];
    else if (g == 1) bs = bih[H + c] + bhh[H + c];
    else if (g == 2) bs = bih[2 * H + c];
    else bs = bhh[2 * H + c];
  }
  coefs[id] = u0;
  coefs[VC + id] = u1;
  coefs[2 * VC + id] = bs;
}

// pack input nodes into npkA; zero pad cols of both buffers
__global__ void init_nodes_kernel(const float* __restrict__ nin,
                                  u32* __restrict__ npkA, u32* __restrict__ npkB) {
  int id = blockIdx.x * 256 + threadIdx.x;
  if (id >= NN * 160) return;
  int r = id / 160, c = id % 160;
  if (c < H) {
    npkA[id] = packf(nin[(size_t)r * H + c]);
  } else {
    npkA[id] = 0;
    npkB[id] = 0;
  }
}

__global__ void pad_S_kernel(u16* __restrict__ Sh, u16* __restrict__ Sl) {
  int id = blockIdx.x * 256 + threadIdx.x;
  if (id >= NN * 20) return;
  int r = id / 20, rem = id % 20;
  int set = rem / 10, t = rem % 10;
  size_t off = (size_t)r * 320 + set * 160 + H + t;
  Sh[off] = 0; Sl[off] = 0;
}

// ---------------- gather: S[n][set*160+c] = sum of raw node rows ----------------
__global__ __launch_bounds__(256) void gather_kernel(
    const u32* __restrict__ npk, const int* __restrict__ rowptr,
    const u16* __restrict__ colbuf, u16* __restrict__ Sh, u16* __restrict__ Sl) {
  int gtid = blockIdx.x * 256 + threadIdx.x;
  int node = gtid >> 6;
  int lane = gtid & 63;
  if (node >= NN) return;
  int s = rowptr[2 * node], mid = rowptr[2 * node + 1], e = rowptr[2 * node + 2];
  int c0 = lane, c1 = lane + 64, c2 = lane + 128;
  bool ok2 = (c2 < H);
  float a0 = 0.f, a1 = 0.f, a2 = 0.f;
  for (int p = s; p < mid; p++) {
    const u32* row = npk + (size_t)colbuf[p] * 160;
    a0 += upk(row[c0]); a1 += upk(row[c1]); if (ok2) a2 += upk(row[c2]);
  }
  float b0 = 0.f, b1 = 0.f, b2 = 0.f;
  for (int p = mid; p < e; p++) {
    const u32* row = npk + (size_t)colbuf[p] * 160;
    b0 += upk(row[c0]); b1 += upk(row[c1]); if (ok2) b2 += upk(row[c2]);
  }
  u16* oh = Sh + (size_t)node * 320;
  u16* ol = Sl + (size_t)node * 320;
  u16 h;
  h = f2bf_rn(a0); oh[c0] = h; ol[c0] = f2bf_rn(a0 - bf2f(h));
  h = f2bf_rn(a1); oh[c1] = h; ol[c1] = f2bf_rn(a1 - bf2f(h));
  if (ok2) { h = f2bf_rn(a2); oh[c2] = h; ol[c2] = f2bf_rn(a2 - bf2f(h)); }
  h = f2bf_rn(b0); oh[160 + c0] = h; ol[160 + c0] = f2bf_rn(b0 - bf2f(h));
  h = f2bf_rn(b1); oh[160 + c1] = h; ol[160 + c1] = f2bf_rn(b1 - bf2f(h));
  if (ok2) { h = f2bf_rn(b2); oh[160 + c2] = h; ol[160 + c2] = f2bf_rn(b2 - bf2f(h)); }
}

// ---------------- fused GRU GEMM: C[NN x 640] = X[NN x 480] @ B'^T, epilogue gates ----
// 128x128 tile, 256 thr / 4 waves; wave w: rows [(w&1)*64,+64) (4 mt) x cols
// [(w>>1)*64,+64) (4 gate-tiles of one c-chunk -> in-register gate combine).
// Phase 1 (kt<10): A = Sh/Sl (separate hi/lo, no repack). Phase 2: A = packed
// node u32 tile, unpacked with shifts (no rounding math). LDS XOR-swizzle.
__global__ __launch_bounds__(256, 3) void gru_gemm_kernel(
    const u16* __restrict__ Sh, const u16* __restrict__ Sl,
    const u32* __restrict__ npkc,
    const u16* __restrict__ Bh, const u16* __restrict__ Bl,
    const float* __restrict__ coefs, const int* __restrict__ rowptr,
    u32* __restrict__ npkn) {
  __shared__ char Abuf[16384];   // p1: [0,8K)=hi,[8K,16K)=lo ; p2: packed u32 tile
  __shared__ char Bbuf[16384];   // [0,8K)=hi, [8K,16K)=lo
  const int r0 = blockIdx.y * 128;
  const int ccb = blockIdx.x;          // vcols [ccb*128, +128)
  const int tid = threadIdx.x;
  const int w = tid >> 6, l = tid & 63;
  const int m = l & 15, quad = l >> 4;
  const int mrow0 = (w & 1) * 64;
  const int nco0 = (w >> 1) * 64;

  float4v acc[4][4];
  #pragma unroll
  for (int mt = 0; mt < 4; mt++)
    #pragma unroll
    for (int j = 0; j < 4; j++) acc[mt][j] = (float4v){0.f, 0.f, 0.f, 0.f};

  #pragma unroll 1
  for (int kt = 0; kt < 15; kt++) {
    // ---- stage B tile (same formula all kts) ----
    #pragma unroll
    for (int i = 0; i < 2; i++) {
      int cl = i * 256 + tid;                     // [0,512)
      int row = cl >> 2;
      int q = (cl & 3) ^ ((row >> 1) & 3);
      size_t gb = (size_t)(ccb * 128 + row) * KB + kt * 32 + q * 8;
      int lb = i * 4096 + w * 1024;
      async16(Bh + gb, Bbuf + lb);
      async16(Bl + gb, Bbuf + 8192 + lb);
    }
    // ---- stage A tile ----
    if (kt < 10) {
      int ko = kt * 32;
      #pragma unroll
      for (int i = 0; i < 2; i++) {
        int cl = i * 256 + tid;
        int row = cl >> 2;
        int q = (cl & 3) ^ ((row >> 1) & 3);
        int rg = min(r0 + row, NN - 1);
        size_t go = (size_t)rg * 320 + ko + q * 8;
        int lb = i * 4096 + w * 1024;
        async16(Sh + go, Abuf + lb);
        async16(Sl + go, Abuf + 8192 + lb);
      }
    } else {
      int ko = kt * 32 - 320;
      #pragma unroll
      for (int i = 0; i < 4; i++) {
        int cl = i * 256 + tid;                   // [0,1024)
        int row = cl >> 3;
        int q = (cl & 7) ^ (row & 7);
        int rg = min(r0 + row, NN - 1);
        async16(npkc + (size_t)rg * 160 + ko + q * 4, Abuf + i * 4096 + w * 1024);
      }
    }
    __syncthreads();
    short8 bh[4], bl[4];
    #pragma unroll
    for (int j = 0; j < 4; j++) {
      int br = nco0 + j * 16 + m;
      int bd = br * 64 + ((quad ^ ((br >> 1) & 3)) * 16);
      bh[j] = *(const short8*)(Bbuf + bd);
      bl[j] = *(const short8*)(Bbuf + 8192 + bd);
    }
    if (kt < 10) {
      #pragma unroll
      for (int mt = 0; mt < 4; mt++) {
        int r = mrow0 + mt * 16 + m;
        int ad = r * 64 + ((quad ^ ((r >> 1) & 3)) * 16);
        short8 ah = *(const short8*)(Abuf + ad);
        short8 al = *(const short8*)(Abuf + 8192 + ad);
        #pragma unroll
        for (int j = 0; j < 4; j++) {
          acc[mt][j] = __builtin_amdgcn_mfma_f32_16x16x32_bf16(ah, bh[j], acc[mt][j], 0, 0, 0);
          acc[mt][j] = __builtin_amdgcn_mfma_f32_16x16x32_bf16(ah, bl[j], acc[mt][j], 0, 0, 0);
          acc[mt][j] = __builtin_amdgcn_mfma_f32_16x16x32_bf16(al, bh[j], acc[mt][j], 0, 0, 0);
        }
      }
    } else {
      #pragma unroll
      for (int mt = 0; mt < 4; mt++) {
        int r = mrow0 + mt * 16 + m;
        uint4v p0 = *(const uint4v*)(Abuf + r * 128 + (((2 * quad) ^ (r & 7)) * 16));
        uint4v p1 = *(const uint4v*)(Abuf + r * 128 + (((2 * quad + 1) ^ (r & 7)) * 16));
        u32 uu[8] = {p0.x, p0.y, p0.z, p0.w, p1.x, p1.y, p1.z, p1.w};
        short8 ah, al;
        #pragma unroll
        for (int e2 = 0; e2 < 8; e2++) {
          ah[e2] = (short)(uu[e2] & 0xffffu);
          al[e2] = (short)(uu[e2] >> 16);
        }
        #pragma unroll
        for (int j = 0; j < 4; j++) {
          acc[mt][j] = __builtin_amdgcn_mfma_f32_16x16x32_bf16(ah, bh[j], acc[mt][j], 0, 0, 0);
          acc[mt][j] = __builtin_amdgcn_mfma_f32_16x16x32_bf16(ah, bl[j], acc[mt][j], 0, 0, 0);
          acc[mt][j] = __builtin_amdgcn_mfma_f32_16x16x32_bf16(al, bh[j], acc[mt][j], 0, 0, 0);
        }
      }
    }
    __syncthreads();
  }

  // ---- epilogue: wave handles c-chunk cc = ccb*2 + (w>>1); tile j = gate ----
  int c = (ccb * 2 + (w >> 1)) * 16 + m;
  if (c >= H) return;
  float u0r = coefs[c],            u0z = coefs[160 + c],
        u0n = coefs[320 + c];
  float u1r = coefs[VC + c],       u1z = coefs[VC + 160 + c],
        u1n = coefs[VC + 320 + c];
  float bsr = coefs[2 * VC + c],   bsz = coefs[2 * VC + 160 + c],
        bsn = coefs[2 * VC + 320 + c], bsh = coefs[2 * VC + 480 + c];
  #pragma unroll
  for (int mt = 0; mt < 4; mt++) {
    #pragma unroll
    for (int i = 0; i < 4; i++) {
      int row = r0 + mrow0 + mt * 16 + quad * 4 + i;
      if (row >= NN) continue;
      float d0 = (float)(rowptr[2 * row + 1] - rowptr[2 * row]);
      float d1 = (float)(rowptr[2 * row + 2] - rowptr[2 * row + 1]);
      float pr = acc[mt][0][i] + d0 * u0r + d1 * u1r + bsr;
      float pz = acc[mt][1][i] + d0 * u0z + d1 * u1z + bsz;
      float pn = acc[mt][2][i] + d0 * u0n + d1 * u1n + bsn;
      float ph = acc[mt][3][i] + bsh;
      float r_g = 1.f / (1.f + __expf(-pr));
      float z_g = 1.f / (1.f + __expf(-pz));
      float narg = pn + r_g * ph;
      float e2 = __expf(2.f * narg);
      float n_g = 1.f - 2.f / (e2 + 1.f);       // tanh, inf-safe
      float h = upk(npkc[(size_t)row * 160 + c]);
      npkn[(size_t)row * 160 + c] = packf((1.f - z_g) * n_g + z_g * h);
    }
  }
}

// ---------------- readout ----------------
__global__ __launch_bounds__(192) void segsum_kernel(const u32* __restrict__ npk,
                                                     const int* __restrict__ gstart,
                                                     float* __restrict__ gsum) {
  int g = blockIdx.x, chunk = blockIdx.y;
  int c = threadIdx.x;
  if (c >= H) return;
  int s = gstart[g], e = gstart[g + 1];
  int len = e - s;
  if (len <= 0) return;
  int per = (len + 3) / 4;
  int rs = s + chunk * per;
  int re = min(e, rs + per);
  if (rs >= re) return;
  float acc = 0.f;
  for (int r = rs; r < re; r++) acc += upk(npk[(size_t)r * 160 + c]);
  atomicAdd(&gsum[g * H + c], acc);
}

__global__ __launch_bounds__(256) void head_kernel(
    const float* __restrict__ gsum, const float* __restrict__ pt,
    const float* __restrict__ fc1_w, const float* __restrict__ fc1_b,
    const float* __restrict__ fc2_w, const float* __restrict__ fc2_b,
    const float* __restrict__ fcL_w, const float* __restrict__ fcL_b,
    float* __restrict__ out) {
  __shared__ float bufA[NG * 151];
  __shared__ float X1[NG * 80];
  int tid = threadIdx.x;
  for (int e = tid; e < NG * 151; e += 256) {
    int row = e / 151, c = e % 151;
    float v;
    if (c < H) { float g = gsum[row * H + c]; v = (g > 1.f) ? logf(g) : 0.f; }
    else v = pt[row];
    bufA[e] = v;
  }
  __syncthreads();
  for (int e = tid; e < NG * 80; e += 256) {
    int row = e / 80, o = e % 80;
    float acc = fc1_b[o];
    for (int k = 0; k < 151; k++) acc += bufA[row * 151 + k] * fc1_w[o * 151 + k];
    X1[e] = (acc > 0.f) ? acc : 0.01f * acc;
  }
  __syncthreads();
  for (int e = tid; e < NG * 80; e += 256) {
    int row = e / 80, o = e % 80;
    float acc = fc2_b[o];
    for (int k = 0; k < 80; k++) acc += X1[row * 80 + k] * fc2_w[o * 80 + k];
    bufA[e] = (acc > 0.f) ? acc : 0.01f * acc;
  }
  __syncthreads();
  for (int e = tid; e < NG * 10; e += 256) {
    int row = e / 10, o = e % 10;
    float acc = fcL_b[o];
    for (int k = 0; k < 80; k++) acc += bufA[row * 80 + k] * fcL_w[o * 80 + k];
    out[e] = acc;
  }
}

extern "C" void kernel_launch(void* const* d_in, const int* in_sizes, int n_in,
                              void* d_out, int out_size, void* d_ws, size_t ws_size,
                              hipStream_t stream) {
  const float* nodes_in = (const float*)d_in[0];
  const float* problem_type = (const float*)d_in[1];
  const float* edge_W = (const float*)d_in[2];
  const float* edge_b = (const float*)d_in[3];
  const float* w_ih = (const float*)d_in[4];
  const float* w_hh = (const float*)d_in[5];
  const float* b_ih = (const float*)d_in[6];
  const float* b_hh = (const float*)d_in[7];
  const float* fc1_w = (const float*)d_in[8];
  const float* fc1_b = (const float*)d_in[9];
  const float* fc2_w = (const float*)d_in[10];
  const float* fc2_b = (const float*)d_in[11];
  const float* fcL_w = (const float*)d_in[12];
  const float* fcL_b = (const float*)d_in[13];
  const int* edges = (const int*)d_in[14];
  const int* graph_ids = (const int*)d_in[15];

  char* ws = (char*)d_ws;
  size_t off = 0;
  auto alloc = [&](size_t bytes) -> void* {
    void* p = ws + off;
    off = (off + bytes + 255) & ~(size_t)255;
    return p;
  };
  u32* npkA     = (u32*)alloc((size_t)NN * 160 * 4);           // 32 MB
  u32* npkB     = (u32*)alloc((size_t)NN * 160 * 4);           // 32 MB
  u16* Sh       = (u16*)alloc((size_t)NN * 320 * 2);           // 32 MB
  u16* Sl       = (u16*)alloc((size_t)NN * 320 * 2);           // 32 MB
  u16* Bh       = (u16*)alloc((size_t)VC * KB * 2);            // 0.61 MB
  u16* Bl       = (u16*)alloc((size_t)VC * KB * 2);            // 0.61 MB
  float* coefs  = (float*)alloc(3 * VC * 4);
  int* rowptr   = (int*)alloc((2 * NN + 1) * 4);
  int* cursor   = (int*)alloc(2 * NN * 4);
  u16* colbuf   = (u16*)alloc(2ull * NE * 2);                  // 1.6 MB
  int* bsum     = (int*)alloc(128 * 4);
  int* boff     = (int*)alloc(128 * 4);
  int* gstart   = (int*)alloc((NG + 1) * 4);
  float* gsum   = (float*)alloc((size_t)NG * H * 4);

  const int n2 = 2 * NN;                 // 100000 counters
  const int nb = (n2 + 1023) / 1024;     // 98 scan blocks

  // ---- one-time setup ----
  hipMemsetAsync(cursor, 0, n2 * 4, stream);
  hist_kernel<<<(2 * NE + 255) / 256, 256, 0, stream>>>(edges, cursor);
  scan1_kernel<<<nb, 1024, 0, stream>>>(cursor, rowptr, bsum, n2);
  scan2_kernel<<<1, 128, 0, stream>>>(bsum, boff, nb);
  scan3_kernel<<<(n2 + 255) / 256, 256, 0, stream>>>(rowptr, boff, n2);
  total_kernel<<<1, 64, 0, stream>>>(rowptr, boff, n2, nb);
  copy_int_kernel<<<(n2 + 255) / 256, 256, 0, stream>>>(rowptr, cursor, n2);
  fill_kernel<<<(2 * NE + 255) / 256, 256, 0, stream>>>(edges, cursor, colbuf);
  bounds_kernel<<<1, 128, 0, stream>>>(graph_ids, gstart);
  build_B_kernel<<<(VC * KB + 255) / 256, 256, 0, stream>>>(w_ih, w_hh, edge_W, Bh, Bl);
  build_coef_kernel<<<(VC + 255) / 256, 256, 0, stream>>>(w_ih, edge_b, b_ih, b_hh, coefs);
  init_nodes_kernel<<<(NN * 160 + 255) / 256, 256, 0, stream>>>(nodes_in, npkA, npkB);
  pad_S_kernel<<<(NN * 20 + 255) / 256, 256, 0, stream>>>(Sh, Sl);

  // ---- 5 message-passing iterations (packed nodes ping-pong) ----
  u32* nbuf[2] = {npkA, npkB};
  for (int pass = 0; pass < NPASS; pass++) {
    u32* cur = nbuf[pass & 1];
    u32* nxt = nbuf[1 - (pass & 1)];
    gather_kernel<<<(NN * 64 + 255) / 256, 256, 0, stream>>>(cur, rowptr, colbuf, Sh, Sl);
    gru_gemm_kernel<<<dim3(VC / 128, (NN + 127) / 128), 256, 0, stream>>>(
        Sh, Sl, cur, Bh, Bl, coefs, rowptr, nxt);
  }
  u32* fin = nbuf[NPASS & 1];

  // ---- readout ----
  hipMemsetAsync(gsum, 0, (size_t)NG * H * 4, stream);
  segsum_kernel<<<dim3(NG, 4), 192, 0, stream>>>(fin, gstart, gsum);
  head_kernel<<<1, 256, 0, stream>>>(gsum, problem_type, fc1_w, fc1_b, fc2_w, fc2_b,
                                     fcL_w, fcL_b, (float*)d_out);
}

// Round 7
// 1702.834 us; speedup vs baseline: 1.6185x; 1.6185x over previous
//
#include <hip/hip_runtime.h>
#include <stdint.h>

#define NN 50000
#define H 150
#define NE 400000
#define NG 64
#define NPASS 5
#define KB 480          // GRU GEMM K: [S0(160) | S1(160) | nodes(160)]
#define VC 640          // 40 col-tiles: v = cc*64 + g*16 + cl, c = cc*16+cl
#define NRB 391         // row blocks of 128

typedef unsigned short u16;
typedef unsigned int u32;
typedef __attribute__((ext_vector_type(8))) short short8;
typedef __attribute__((ext_vector_type(4))) float float4v;
typedef __attribute__((ext_vector_type(4))) u32 uint4v;

// ---------------- helpers ----------------
__device__ __forceinline__ u16 f2bf_rn(float x) {
  union { float f; u32 u; } v; v.f = x;
  u32 r = v.u + 0x7fffu + ((v.u >> 16) & 1u);
  return (u16)(r >> 16);
}
__device__ __forceinline__ float bf2f(u16 h) {
  union { u32 u; float f; } v; v.u = ((u32)h) << 16;
  return v.f;
}
// packed node word: low16 = hi bf16, high16 = lo bf16; value = hi + lo
__device__ __forceinline__ u32 packf(float v) {
  u16 hi = f2bf_rn(v);
  u16 lo = f2bf_rn(v - bf2f(hi));
  return (u32)hi | ((u32)lo << 16);
}
__device__ __forceinline__ float upk(u32 u) {
  union { u32 u; float f; } a, b;
  a.u = u << 16; b.u = u & 0xffff0000u;
  return a.f + b.f;
}
// async global->LDS, 16B per lane; lds dest must be wave-uniform base
__device__ __forceinline__ void async16(const void* g, void* l) {
  __builtin_amdgcn_global_load_lds(
      (const __attribute__((address_space(1))) unsigned int*)(uintptr_t)g,
      (__attribute__((address_space(3))) unsigned int*)(uint32_t)(uintptr_t)l,
      16, 0, 0);
}

// ---------------- CSR build (key = node*2 + set) ----------------
__global__ void hist_kernel(const int* __restrict__ edges, int* __restrict__ cnt) {
  int id = blockIdx.x * 256 + threadIdx.x;
  if (id >= 2 * NE) return;
  int dst = edges[id * 2];
  int set = id / NE;
  atomicAdd(&cnt[dst * 2 + set], 1);
}

__global__ __launch_bounds__(1024) void scan1_kernel(const int* __restrict__ cnt,
                                                     int* __restrict__ rowptr,
                                                     int* __restrict__ bsum, int n) {
  __shared__ int sd[1024];
  int t = threadIdx.x;
  int idx = blockIdx.x * 1024 + t;
  int v = (idx < n) ? cnt[idx] : 0;
  sd[t] = v;
  __syncthreads();
  for (int off = 1; off < 1024; off <<= 1) {
    int add = (t >= off) ? sd[t - off] : 0;
    __syncthreads();
    sd[t] += add;
    __syncthreads();
  }
  if (idx < n) rowptr[idx] = sd[t] - v;     // block-local exclusive
  if (t == 1023) bsum[blockIdx.x] = sd[1023];
}

__global__ __launch_bounds__(128) void scan2_kernel(const int* __restrict__ bsum,
                                                    int* __restrict__ boff, int nb) {
  __shared__ int sd[128];
  int t = threadIdx.x;
  int v = (t < nb) ? bsum[t] : 0;
  sd[t] = v;
  __syncthreads();
  for (int off = 1; off < 128; off <<= 1) {
    int add = (t >= off) ? sd[t - off] : 0;
    __syncthreads();
    sd[t] += add;
    __syncthreads();
  }
  boff[t] = sd[t] - v;                       // exclusive; boff[nb] = total
}

__global__ void scan3_kernel(int* __restrict__ rowptr, const int* __restrict__ boff, int n) {
  int idx = blockIdx.x * 256 + threadIdx.x;
  if (idx < n) rowptr[idx] += boff[idx >> 10];
}

__global__ void total_kernel(int* __restrict__ rowptr, const int* __restrict__ boff, int n, int nb) {
  if (threadIdx.x == 0 && blockIdx.x == 0) rowptr[n] = boff[nb];
}

__global__ void copy_int_kernel(const int* __restrict__ a, int* __restrict__ b, int n) {
  int id = blockIdx.x * 256 + threadIdx.x;
  if (id < n) b[id] = a[id];
}

__global__ void fill_kernel(const int* __restrict__ edges, int* __restrict__ cursor,
                            u16* __restrict__ colbuf) {
  int id = blockIdx.x * 256 + threadIdx.x;
  if (id >= 2 * NE) return;
  int dst = edges[id * 2];
  int src = edges[id * 2 + 1];
  int set = id / NE;
  int pos = atomicAdd(&cursor[dst * 2 + set], 1);
  colbuf[pos] = (u16)src;
}

__global__ void bounds_kernel(const int* __restrict__ gids, int* __restrict__ gstart) {
  int g = threadIdx.x;
  if (g > NG) return;
  int lo = 0, hi = NN;
  while (lo < hi) { int m = (lo + hi) >> 1; if (gids[m] < g) lo = m + 1; else hi = m; }
  gstart[g] = lo;
}

// ---------------- one-time weight prep ----------------
// B'[v][k], v in [0,640): g=(v>>4)&3, c=(v>>6)*16+(v&15)
// k<160: (W_ihg @ W0)[c][k]      (g<3; g3=0)
// 160<=k<320: (W_ihg @ W1)[c][k-160]
// 320<=k<480: g0: w_hh[c][kk], g1: w_hh[150+c][kk], g3: w_hh[300+c][kk], g2: 0
__global__ void build_B_kernel(const float* __restrict__ wih, const float* __restrict__ whh,
                               const float* __restrict__ eW,
                               u16* __restrict__ Bh, u16* __restrict__ Bl) {
  int id = blockIdx.x * 256 + threadIdx.x;
  if (id >= VC * KB) return;
  int v = id / KB, k = id % KB;
  int g = (v >> 4) & 3, c = (v >> 6) * 16 + (v & 15);
  int seg = k / 160, kk = k % 160;
  float val = 0.f;
  if (c < H && kk < H) {
    if (seg < 2) {
      if (g < 3) {
        const float* wr = wih + (size_t)(g * H + c) * H;
        const float* wc = eW + (size_t)seg * H * H + kk;
        float acc = 0.f;
        for (int t = 0; t < H; t++) acc += wr[t] * wc[(size_t)t * H];
        val = acc;
      }
    } else {
      if (g == 0) val = whh[(size_t)c * H + kk];
      else if (g == 1) val = whh[(size_t)(H + c) * H + kk];
      else if (g == 3) val = whh[(size_t)(2 * H + c) * H + kk];
    }
  }
  u16 h = f2bf_rn(val);
  Bh[id] = h;
  Bl[id] = f2bf_rn(val - bf2f(h));
}

// coefs[0][g*160+c] = W_ihg @ b0 (deg0 coef), coefs[1] = W_ihg @ b1, coefs[2] = gate bias
__global__ void build_coef_kernel(const float* __restrict__ wih,
                                  const float* __restrict__ eb,
                                  const float* __restrict__ bih, const float* __restrict__ bhh,
                                  float* __restrict__ coefs) {
  int id = threadIdx.x + blockIdx.x * 256;
  if (id >= VC) return;
  int g = id / 160, c = id % 160;
  float u0 = 0.f, u1 = 0.f, bs = 0.f;
  if (c < H) {
    if (g < 3) {
      const float* wr = wih + (size_t)(g * H + c) * H;
      for (int t = 0; t < H; t++) { u0 += wr[t] * eb[t]; u1 += wr[t] * eb[H + t]; }
    }
    if (g == 0) bs = bih[c] + bhh[c];
    else if (g == 1) bs = bih[H + c] + bhh[H + c];
    else if (g == 2) bs = bih[2 * H + c];
    else bs = bhh[2 * H + c];
  }
  coefs[id] = u0;
  coefs[VC + id] = u1;
  coefs[2 * VC + id] = bs;
}

// pack input nodes into npkA; zero pad cols of both buffers
__global__ void init_nodes_kernel(const float* __restrict__ nin,
                                  u32* __restrict__ npkA, u32* __restrict__ npkB) {
  int id = blockIdx.x * 256 + threadIdx.x;
  if (id >= NN * 160) return;
  int r = id / 160, c = id % 160;
  if (c < H) {
    npkA[id] = packf(nin[(size_t)r * H + c]);
  } else {
    npkA[id] = 0;
    npkB[id] = 0;
  }
}

__global__ void pad_S_kernel(u16* __restrict__ Sh, u16* __restrict__ Sl) {
  int id = blockIdx.x * 256 + threadIdx.x;
  if (id >= NN * 20) return;
  int r = id / 20, rem = id % 20;
  int set = rem / 10, t = rem % 10;
  size_t off = (size_t)r * 320 + set * 160 + H + t;
  Sh[off] = 0; Sl[off] = 0;
}

// ---------------- gather: S[n][set*160+c] = sum of raw node rows ----------------
__global__ __launch_bounds__(256) void gather_kernel(
    const u32* __restrict__ npk, const int* __restrict__ rowptr,
    const u16* __restrict__ colbuf, u16* __restrict__ Sh, u16* __restrict__ Sl) {
  int gtid = blockIdx.x * 256 + threadIdx.x;
  int node = gtid >> 6;
  int lane = gtid & 63;
  if (node >= NN) return;
  int s = rowptr[2 * node], mid = rowptr[2 * node + 1], e = rowptr[2 * node + 2];
  int c0 = lane, c1 = lane + 64, c2 = lane + 128;
  bool ok2 = (c2 < H);
  float a0 = 0.f, a1 = 0.f, a2 = 0.f;
  for (int p = s; p < mid; p++) {
    const u32* row = npk + (size_t)colbuf[p] * 160;
    a0 += upk(row[c0]); a1 += upk(row[c1]); if (ok2) a2 += upk(row[c2]);
  }
  float b0 = 0.f, b1 = 0.f, b2 = 0.f;
  for (int p = mid; p < e; p++) {
    const u32* row = npk + (size_t)colbuf[p] * 160;
    b0 += upk(row[c0]); b1 += upk(row[c1]); if (ok2) b2 += upk(row[c2]);
  }
  u16* oh = Sh + (size_t)node * 320;
  u16* ol = Sl + (size_t)node * 320;
  u16 h;
  h = f2bf_rn(a0); oh[c0] = h; ol[c0] = f2bf_rn(a0 - bf2f(h));
  h = f2bf_rn(a1); oh[c1] = h; ol[c1] = f2bf_rn(a1 - bf2f(h));
  if (ok2) { h = f2bf_rn(a2); oh[c2] = h; ol[c2] = f2bf_rn(a2 - bf2f(h)); }
  h = f2bf_rn(b0); oh[160 + c0] = h; ol[160 + c0] = f2bf_rn(b0 - bf2f(h));
  h = f2bf_rn(b1); oh[160 + c1] = h; ol[160 + c1] = f2bf_rn(b1 - bf2f(h));
  if (ok2) { h = f2bf_rn(b2); oh[160 + c2] = h; ol[160 + c2] = f2bf_rn(b2 - bf2f(h)); }
}

// ---------------- fused GRU GEMM: C[NN x 640] = X[NN x 480] @ B'^T, epilogue gates ----
// R5-proven shape: 128x128 tile, 128 thr / 2 waves; wave w: ALL 8 m-tiles x
// 4 n-tiles (cols [w*64,+64) = one c-chunk x 4 gates, in-register combine).
// XCD swizzle: flat bid -> xcd = bid&7; r0b = (bid>>3)/5*8 + xcd; ccb = (bid>>3)%5
// so the 5 col-blocks sharing an A-slab land on ONE XCD -> A fetched once/L2-hit.
// Phase 2 A = packed u32 nodes, shift-unpack (no rounding VALU).
__global__ __launch_bounds__(128) void gru_gemm_kernel(
    const u16* __restrict__ Sh, const u16* __restrict__ Sl,
    const u32* __restrict__ npkc,
    const u16* __restrict__ Bh, const u16* __restrict__ Bl,
    const float* __restrict__ coefs, const int* __restrict__ rowptr,
    u32* __restrict__ npkn) {
  __shared__ char Abuf[16384];   // p1: [0,8K)=hi,[8K,16K)=lo ; p2: packed u32 tile
  __shared__ char Bbuf[16384];   // [0,8K)=hi, [8K,16K)=lo
  const int bid = blockIdx.x;
  const int xcd = bid & 7;
  const int rest = bid >> 3;
  const int ccb = rest % 5;
  const int r0b = (rest / 5) * 8 + xcd;
  if (r0b >= NRB) return;
  const int r0 = r0b * 128;
  const int tid = threadIdx.x;
  const int w = tid >> 6, l = tid & 63;
  const int m = l & 15, quad = l >> 4;

  float4v acc[8][4];
  #pragma unroll
  for (int mt = 0; mt < 8; mt++)
    #pragma unroll
    for (int j = 0; j < 4; j++) acc[mt][j] = (float4v){0.f, 0.f, 0.f, 0.f};

  // ---- K phase 1: S half (bf16 hi/lo), kt 0..9 ----
  #pragma unroll 1
  for (int kt = 0; kt < 10; kt++) {
    int koff = kt * 32;
    #pragma unroll
    for (int i = 0; i < 4; i++) {
      int cl = i * 128 + tid;                     // [0,512)
      int row = cl >> 2;
      int q = (cl & 3) ^ ((row >> 1) & 3);
      int rg = min(r0 + row, NN - 1);
      size_t go = (size_t)rg * 320 + koff + q * 8;
      int lb = i * 2048 + w * 1024;
      async16(Sh + go, Abuf + lb);
      async16(Sl + go, Abuf + 8192 + lb);
      size_t gb = (size_t)(ccb * 128 + row) * KB + koff + q * 8;
      async16(Bh + gb, Bbuf + lb);
      async16(Bl + gb, Bbuf + 8192 + lb);
    }
    __syncthreads();
    short8 bh[4], bl[4];
    #pragma unroll
    for (int j = 0; j < 4; j++) {
      int br = w * 64 + j * 16 + m;
      int bd = br * 64 + ((quad ^ ((br >> 1) & 3)) * 16);
      bh[j] = *(const short8*)(Bbuf + bd);
      bl[j] = *(const short8*)(Bbuf + 8192 + bd);
    }
    #pragma unroll
    for (int mt = 0; mt < 8; mt++) {
      int r = mt * 16 + m;
      int ad = r * 64 + ((quad ^ ((r >> 1) & 3)) * 16);
      short8 ah = *(const short8*)(Abuf + ad);
      short8 al = *(const short8*)(Abuf + 8192 + ad);
      #pragma unroll
      for (int j = 0; j < 4; j++) {
        acc[mt][j] = __builtin_amdgcn_mfma_f32_16x16x32_bf16(ah, bh[j], acc[mt][j], 0, 0, 0);
        acc[mt][j] = __builtin_amdgcn_mfma_f32_16x16x32_bf16(ah, bl[j], acc[mt][j], 0, 0, 0);
        acc[mt][j] = __builtin_amdgcn_mfma_f32_16x16x32_bf16(al, bh[j], acc[mt][j], 0, 0, 0);
      }
    }
    __syncthreads();
  }

  // ---- K phase 2: nodes half (packed u32, shift-unpack), kt 10..14 ----
  #pragma unroll 1
  for (int kt = 0; kt < 5; kt++) {
    int koff = kt * 32;
    #pragma unroll
    for (int i = 0; i < 8; i++) {
      int cl = i * 128 + tid;                     // [0,1024)
      int row = cl >> 3;
      int q = (cl & 7) ^ (row & 7);
      int rg = min(r0 + row, NN - 1);
      async16(npkc + (size_t)rg * 160 + koff + q * 4, Abuf + i * 2048 + w * 1024);
    }
    #pragma unroll
    for (int i = 0; i < 4; i++) {
      int cl = i * 128 + tid;
      int row = cl >> 2;
      int q = (cl & 3) ^ ((row >> 1) & 3);
      size_t gb = (size_t)(ccb * 128 + row) * KB + 320 + koff + q * 8;
      int lb = i * 2048 + w * 1024;
      async16(Bh + gb, Bbuf + lb);
      async16(Bl + gb, Bbuf + 8192 + lb);
    }
    __syncthreads();
    short8 bh[4], bl[4];
    #pragma unroll
    for (int j = 0; j < 4; j++) {
      int br = w * 64 + j * 16 + m;
      int bd = br * 64 + ((quad ^ ((br >> 1) & 3)) * 16);
      bh[j] = *(const short8*)(Bbuf + bd);
      bl[j] = *(const short8*)(Bbuf + 8192 + bd);
    }
    #pragma unroll
    for (int mt = 0; mt < 8; mt++) {
      int r = mt * 16 + m;
      uint4v p0 = *(const uint4v*)(Abuf + r * 128 + (((2 * quad) ^ (r & 7)) * 16));
      uint4v p1 = *(const uint4v*)(Abuf + r * 128 + (((2 * quad + 1) ^ (r & 7)) * 16));
      u32 uu[8] = {p0.x, p0.y, p0.z, p0.w, p1.x, p1.y, p1.z, p1.w};
      short8 ah, al;
      #pragma unroll
      for (int e2 = 0; e2 < 8; e2++) {
        ah[e2] = (short)(uu[e2] & 0xffffu);
        al[e2] = (short)(uu[e2] >> 16);
      }
      #pragma unroll
      for (int j = 0; j < 4; j++) {
        acc[mt][j] = __builtin_amdgcn_mfma_f32_16x16x32_bf16(ah, bh[j], acc[mt][j], 0, 0, 0);
        acc[mt][j] = __builtin_amdgcn_mfma_f32_16x16x32_bf16(ah, bl[j], acc[mt][j], 0, 0, 0);
        acc[mt][j] = __builtin_amdgcn_mfma_f32_16x16x32_bf16(al, bh[j], acc[mt][j], 0, 0, 0);
      }
    }
    __syncthreads();
  }

  // ---- epilogue: gate math; wave w handles c-chunk cc=2*ccb+w, tiles j = gate ----
  int c = (2 * ccb + w) * 16 + m;
  if (c >= H) return;
  float u0r = coefs[c],            u0z = coefs[160 + c],
        u0n = coefs[320 + c];
  float u1r = coefs[VC + c],       u1z = coefs[VC + 160 + c],
        u1n = coefs[VC + 320 + c];
  float bsr = coefs[2 * VC + c],   bsz = coefs[2 * VC + 160 + c],
        bsn = coefs[2 * VC + 320 + c], bsh = coefs[2 * VC + 480 + c];
  #pragma unroll
  for (int mt = 0; mt < 8; mt++) {
    #pragma unroll
    for (int i = 0; i < 4; i++) {
      int row = r0 + mt * 16 + quad * 4 + i;
      if (row >= NN) continue;
      float d0 = (float)(rowptr[2 * row + 1] - rowptr[2 * row]);
      float d1 = (float)(rowptr[2 * row + 2] - rowptr[2 * row + 1]);
      float pr = acc[mt][0][i] + d0 * u0r + d1 * u1r + bsr;
      float pz = acc[mt][1][i] + d0 * u0z + d1 * u1z + bsz;
      float pn = acc[mt][2][i] + d0 * u0n + d1 * u1n + bsn;
      float ph = acc[mt][3][i] + bsh;
      float r_g = 1.f / (1.f + __expf(-pr));
      float z_g = 1.f / (1.f + __expf(-pz));
      float narg = pn + r_g * ph;
      float e2 = __expf(2.f * narg);
      float n_g = 1.f - 2.f / (e2 + 1.f);       // tanh, inf-safe
      float h = upk(npkc[(size_t)row * 160 + c]);
      npkn[(size_t)row * 160 + c] = packf((1.f - z_g) * n_g + z_g * h);
    }
  }
}

// ---------------- readout ----------------
__global__ __launch_bounds__(192) void segsum_kernel(const u32* __restrict__ npk,
                                                     const int* __restrict__ gstart,
                                                     float* __restrict__ gsum) {
  int g = blockIdx.x, chunk = blockIdx.y;
  int c = threadIdx.x;
  if (c >= H) return;
  int s = gstart[g], e = gstart[g + 1];
  int len = e - s;
  if (len <= 0) return;
  int per = (len + 3) / 4;
  int rs = s + chunk * per;
  int re = min(e, rs + per);
  if (rs >= re) return;
  float acc = 0.f;
  for (int r = rs; r < re; r++) acc += upk(npk[(size_t)r * 160 + c]);
  atomicAdd(&gsum[g * H + c], acc);
}

__global__ __launch_bounds__(256) void head_kernel(
    const float* __restrict__ gsum, const float* __restrict__ pt,
    const float* __restrict__ fc1_w, const float* __restrict__ fc1_b,
    const float* __restrict__ fc2_w, const float* __restrict__ fc2_b,
    const float* __restrict__ fcL_w, const float* __restrict__ fcL_b,
    float* __restrict__ out) {
  __shared__ float bufA[NG * 151];
  __shared__ float X1[NG * 80];
  int tid = threadIdx.x;
  for (int e = tid; e < NG * 151; e += 256) {
    int row = e / 151, c = e % 151;
    float v;
    if (c < H) { float g = gsum[row * H + c]; v = (g > 1.f) ? logf(g) : 0.f; }
    else v = pt[row];
    bufA[e] = v;
  }
  __syncthreads();
  for (int e = tid; e < NG * 80; e += 256) {
    int row = e / 80, o = e % 80;
    float acc = fc1_b[o];
    for (int k = 0; k < 151; k++) acc += bufA[row * 151 + k] * fc1_w[o * 151 + k];
    X1[e] = (acc > 0.f) ? acc : 0.01f * acc;
  }
  __syncthreads();
  for (int e = tid; e < NG * 80; e += 256) {
    int row = e / 80, o = e % 80;
    float acc = fc2_b[o];
    for (int k = 0; k < 80; k++) acc += X1[row * 80 + k] * fc2_w[o * 80 + k];
    bufA[e] = (acc > 0.f) ? acc : 0.01f * acc;
  }
  __syncthreads();
  for (int e = tid; e < NG * 10; e += 256) {
    int row = e / 10, o = e % 10;
    float acc = fcL_b[o];
    for (int k = 0; k < 80; k++) acc += bufA[row * 80 + k] * fcL_w[o * 80 + k];
    out[e] = acc;
  }
}

extern "C" void kernel_launch(void* const* d_in, const int* in_sizes, int n_in,
                              void* d_out, int out_size, void* d_ws, size_t ws_size,
                              hipStream_t stream) {
  const float* nodes_in = (const float*)d_in[0];
  const float* problem_type = (const float*)d_in[1];
  const float* edge_W = (const float*)d_in[2];
  const float* edge_b = (const float*)d_in[3];
  const float* w_ih = (const float*)d_in[4];
  const float* w_hh = (const float*)d_in[5];
  const float* b_ih = (const float*)d_in[6];
  const float* b_hh = (const float*)d_in[7];
  const float* fc1_w = (const float*)d_in[8];
  const float* fc1_b = (const float*)d_in[9];
  const float* fc2_w = (const float*)d_in[10];
  const float* fc2_b = (const float*)d_in[11];
  const float* fcL_w = (const float*)d_in[12];
  const float* fcL_b = (const float*)d_in[13];
  const int* edges = (const int*)d_in[14];
  const int* graph_ids = (const int*)d_in[15];

  char* ws = (char*)d_ws;
  size_t off = 0;
  auto alloc = [&](size_t bytes) -> void* {
    void* p = ws + off;
    off = (off + bytes + 255) & ~(size_t)255;
    return p;
  };
  u32* npkA     = (u32*)alloc((size_t)NN * 160 * 4);           // 32 MB
  u32* npkB     = (u32*)alloc((size_t)NN * 160 * 4);           // 32 MB
  u16* Sh       = (u16*)alloc((size_t)NN * 320 * 2);           // 32 MB
  u16* Sl       = (u16*)alloc((size_t)NN * 320 * 2);           // 32 MB
  u16* Bh       = (u16*)alloc((size_t)VC * KB * 2);            // 0.61 MB
  u16* Bl       = (u16*)alloc((size_t)VC * KB * 2);            // 0.61 MB
  float* coefs  = (float*)alloc(3 * VC * 4);
  int* rowptr   = (int*)alloc((2 * NN + 1) * 4);
  int* cursor   = (int*)alloc(2 * NN * 4);
  u16* colbuf   = (u16*)alloc(2ull * NE * 2);                  // 1.6 MB
  int* bsum     = (int*)alloc(128 * 4);
  int* boff     = (int*)alloc(128 * 4);
  int* gstart   = (int*)alloc((NG + 1) * 4);
  float* gsum   = (float*)alloc((size_t)NG * H * 4);

  const int n2 = 2 * NN;                 // 100000 counters
  const int nb = (n2 + 1023) / 1024;     // 98 scan blocks

  // ---- one-time setup ----
  hipMemsetAsync(cursor, 0, n2 * 4, stream);
  hist_kernel<<<(2 * NE + 255) / 256, 256, 0, stream>>>(edges, cursor);
  scan1_kernel<<<nb, 1024, 0, stream>>>(cursor, rowptr, bsum, n2);
  scan2_kernel<<<1, 128, 0, stream>>>(bsum, boff, nb);
  scan3_kernel<<<(n2 + 255) / 256, 256, 0, stream>>>(rowptr, boff, n2);
  total_kernel<<<1, 64, 0, stream>>>(rowptr, boff, n2, nb);
  copy_int_kernel<<<(n2 + 255) / 256, 256, 0, stream>>>(rowptr, cursor, n2);
  fill_kernel<<<(2 * NE + 255) / 256, 256, 0, stream>>>(edges, cursor, colbuf);
  bounds_kernel<<<1, 128, 0, stream>>>(graph_ids, gstart);
  build_B_kernel<<<(VC * KB + 255) / 256, 256, 0, stream>>>(w_ih, w_hh, edge_W, Bh, Bl);
  build_coef_kernel<<<(VC + 255) / 256, 256, 0, stream>>>(w_ih, edge_b, b_ih, b_hh, coefs);
  init_nodes_kernel<<<(NN * 160 + 255) / 256, 256, 0, stream>>>(nodes_in, npkA, npkB);
  pad_S_kernel<<<(NN * 20 + 255) / 256, 256, 0, stream>>>(Sh, Sl);

  // ---- 5 message-passing iterations (packed nodes ping-pong) ----
  const int ngrp = (NRB + 7) / 8;        // 49 groups of 8 row-blocks
  u32* nbuf[2] = {npkA, npkB};
  for (int pass = 0; pass < NPASS; pass++) {
    u32* cur = nbuf[pass & 1];
    u32* nxt = nbuf[1 - (pass & 1)];
    gather_kernel<<<(NN * 64 + 255) / 256, 256, 0, stream>>>(cur, rowptr, colbuf, Sh, Sl);
    gru_gemm_kernel<<<ngrp * 5 * 8, 128, 0, stream>>>(
        Sh, Sl, cur, Bh, Bl, coefs, rowptr, nxt);
  }
  u32* fin = nbuf[NPASS & 1];

  // ---- readout ----
  hipMemsetAsync(gsum, 0, (size_t)NG * H * 4, stream);
  segsum_kernel<<<dim3(NG, 4), 192, 0, stream>>>(fin, gstart, gsum);
  head_kernel<<<1, 256, 0, stream>>>(gsum, problem_type, fc1_w, fc1_b, fc2_w, fc2_b,
                                     fcL_w, fcL_b, (float*)d_out);
}

// Round 8
// 1612.112 us; speedup vs baseline: 1.7096x; 1.0563x over previous
//
#include <hip/hip_runtime.h>
#include <stdint.h>

#define NN 50000
#define H 150
#define NE 400000
#define NG 64
#define NPASS 5
#define KB 480          // GRU GEMM K: [S0(160) | S1(160) | nodes(160)]
#define VC 640          // 40 col-tiles: v = cc*64 + g*16 + cl, c = cc*16+cl
#define NRB 391         // row blocks of 128

typedef unsigned short u16;
typedef unsigned int u32;
typedef __attribute__((ext_vector_type(8))) short short8;
typedef __attribute__((ext_vector_type(4))) float float4v;
typedef __attribute__((ext_vector_type(4))) u32 uint4v;

// ---------------- helpers ----------------
__device__ __forceinline__ u16 f2bf_rn(float x) {
  union { float f; u32 u; } v; v.f = x;
  u32 r = v.u + 0x7fffu + ((v.u >> 16) & 1u);
  return (u16)(r >> 16);
}
__device__ __forceinline__ float bf2f(u16 h) {
  union { u32 u; float f; } v; v.u = ((u32)h) << 16;
  return v.f;
}
// packed node word: low16 = hi bf16, high16 = lo bf16; value = hi + lo
__device__ __forceinline__ u32 packf(float v) {
  u16 hi = f2bf_rn(v);
  u16 lo = f2bf_rn(v - bf2f(hi));
  return (u32)hi | ((u32)lo << 16);
}
__device__ __forceinline__ float upk(u32 u) {
  union { u32 u; float f; } a, b;
  a.u = u << 16; b.u = u & 0xffff0000u;
  return a.f + b.f;
}
// async global->LDS, 16B per lane; lds dest must be wave-uniform base
__device__ __forceinline__ void async16(const void* g, void* l) {
  __builtin_amdgcn_global_load_lds(
      (const __attribute__((address_space(1))) unsigned int*)(uintptr_t)g,
      (__attribute__((address_space(3))) unsigned int*)(uint32_t)(uintptr_t)l,
      16, 0, 0);
}

// ---------------- CSR build (key = node*2 + set) ----------------
__global__ void hist_kernel(const int* __restrict__ edges, int* __restrict__ cnt) {
  int id = blockIdx.x * 256 + threadIdx.x;
  if (id >= 2 * NE) return;
  int dst = edges[id * 2];
  int set = id / NE;
  atomicAdd(&cnt[dst * 2 + set], 1);
}

__global__ __launch_bounds__(1024) void scan1_kernel(const int* __restrict__ cnt,
                                                     int* __restrict__ rowptr,
                                                     int* __restrict__ bsum, int n) {
  __shared__ int sd[1024];
  int t = threadIdx.x;
  int idx = blockIdx.x * 1024 + t;
  int v = (idx < n) ? cnt[idx] : 0;
  sd[t] = v;
  __syncthreads();
  for (int off = 1; off < 1024; off <<= 1) {
    int add = (t >= off) ? sd[t - off] : 0;
    __syncthreads();
    sd[t] += add;
    __syncthreads();
  }
  if (idx < n) rowptr[idx] = sd[t] - v;     // block-local exclusive
  if (t == 1023) bsum[blockIdx.x] = sd[1023];
}

__global__ __launch_bounds__(128) void scan2_kernel(const int* __restrict__ bsum,
                                                    int* __restrict__ boff, int nb) {
  __shared__ int sd[128];
  int t = threadIdx.x;
  int v = (t < nb) ? bsum[t] : 0;
  sd[t] = v;
  __syncthreads();
  for (int off = 1; off < 128; off <<= 1) {
    int add = (t >= off) ? sd[t - off] : 0;
    __syncthreads();
    sd[t] += add;
    __syncthreads();
  }
  boff[t] = sd[t] - v;                       // exclusive; boff[nb] = total
}

__global__ void scan3_kernel(int* __restrict__ rowptr, const int* __restrict__ boff, int n) {
  int idx = blockIdx.x * 256 + threadIdx.x;
  if (idx < n) rowptr[idx] += boff[idx >> 10];
}

__global__ void total_kernel(int* __restrict__ rowptr, const int* __restrict__ boff, int n, int nb) {
  if (threadIdx.x == 0 && blockIdx.x == 0) rowptr[n] = boff[nb];
}

__global__ void copy_int_kernel(const int* __restrict__ a, int* __restrict__ b, int n) {
  int id = blockIdx.x * 256 + threadIdx.x;
  if (id < n) b[id] = a[id];
}

__global__ void fill_kernel(const int* __restrict__ edges, int* __restrict__ cursor,
                            u16* __restrict__ colbuf) {
  int id = blockIdx.x * 256 + threadIdx.x;
  if (id >= 2 * NE) return;
  int dst = edges[id * 2];
  int src = edges[id * 2 + 1];
  int set = id / NE;
  int pos = atomicAdd(&cursor[dst * 2 + set], 1);
  colbuf[pos] = (u16)src;
}

__global__ void bounds_kernel(const int* __restrict__ gids, int* __restrict__ gstart) {
  int g = threadIdx.x;
  if (g > NG) return;
  int lo = 0, hi = NN;
  while (lo < hi) { int m = (lo + hi) >> 1; if (gids[m] < g) lo = m + 1; else hi = m; }
  gstart[g] = lo;
}

// ---------------- one-time weight prep ----------------
// B'[v][k], v in [0,640): g=(v>>4)&3, c=(v>>6)*16+(v&15)
// k<160: (W_ihg @ W0)[c][k]      (g<3; g3=0)
// 160<=k<320: (W_ihg @ W1)[c][k-160]
// 320<=k<480: g0: w_hh[c][kk], g1: w_hh[150+c][kk], g3: w_hh[300+c][kk], g2: 0
__global__ void build_B_kernel(const float* __restrict__ wih, const float* __restrict__ whh,
                               const float* __restrict__ eW,
                               u16* __restrict__ Bh, u16* __restrict__ Bl) {
  int id = blockIdx.x * 256 + threadIdx.x;
  if (id >= VC * KB) return;
  int v = id / KB, k = id % KB;
  int g = (v >> 4) & 3, c = (v >> 6) * 16 + (v & 15);
  int seg = k / 160, kk = k % 160;
  float val = 0.f;
  if (c < H && kk < H) {
    if (seg < 2) {
      if (g < 3) {
        const float* wr = wih + (size_t)(g * H + c) * H;
        const float* wc = eW + (size_t)seg * H * H + kk;
        float acc = 0.f;
        for (int t = 0; t < H; t++) acc += wr[t] * wc[(size_t)t * H];
        val = acc;
      }
    } else {
      if (g == 0) val = whh[(size_t)c * H + kk];
      else if (g == 1) val = whh[(size_t)(H + c) * H + kk];
      else if (g == 3) val = whh[(size_t)(2 * H + c) * H + kk];
    }
  }
  u16 h = f2bf_rn(val);
  Bh[id] = h;
  Bl[id] = f2bf_rn(val - bf2f(h));
}

// coefs[0][g*160+c] = W_ihg @ b0 (deg0 coef), coefs[1] = W_ihg @ b1, coefs[2] = gate bias
__global__ void build_coef_kernel(const float* __restrict__ wih,
                                  const float* __restrict__ eb,
                                  const float* __restrict__ bih, const float* __restrict__ bhh,
                                  float* __restrict__ coefs) {
  int id = threadIdx.x + blockIdx.x * 256;
  if (id >= VC) return;
  int g = id / 160, c = id % 160;
  float u0 = 0.f, u1 = 0.f, bs = 0.f;
  if (c < H) {
    if (g < 3) {
      const float* wr = wih + (size_t)(g * H + c) * H;
      for (int t = 0; t < H; t++) { u0 += wr[t] * eb[t]; u1 += wr[t] * eb[H + t]; }
    }
    if (g == 0) bs = bih[c] + bhh[c];
    else if (g == 1) bs = bih[H + c] + bhh[H + c];
    else if (g == 2) bs = bih[2 * H + c];
    else bs = bhh[2 * H + c];
  }
  coefs[id] = u0;
  coefs[VC + id] = u1;
  coefs[2 * VC + id] = bs;
}

// pack input nodes into npkA; zero pad cols of both buffers
__global__ void init_nodes_kernel(const float* __restrict__ nin,
                                  u32* __restrict__ npkA, u32* __restrict__ npkB) {
  int id = blockIdx.x * 256 + threadIdx.x;
  if (id >= NN * 160) return;
  int r = id / 160, c = id % 160;
  if (c < H) {
    npkA[id] = packf(nin[(size_t)r * H + c]);
  } else {
    npkA[id] = 0;
    npkB[id] = 0;
  }
}

__global__ void pad_S_kernel(u16* __restrict__ Sh, u16* __restrict__ Sl) {
  int id = blockIdx.x * 256 + threadIdx.x;
  if (id >= NN * 20) return;
  int r = id / 20, rem = id % 20;
  int set = rem / 10, t = rem % 10;
  size_t off = (size_t)r * 320 + set * 160 + H + t;
  Sh[off] = 0; Sl[off] = 0;
}

// ---------------- gather: S[n][set*160+c] = sum of raw node rows ----------------
__global__ __launch_bounds__(256) void gather_kernel(
    const u32* __restrict__ npk, const int* __restrict__ rowptr,
    const u16* __restrict__ colbuf, u16* __restrict__ Sh, u16* __restrict__ Sl) {
  int gtid = blockIdx.x * 256 + threadIdx.x;
  int node = gtid >> 6;
  int lane = gtid & 63;
  if (node >= NN) return;
  int s = rowptr[2 * node], mid = rowptr[2 * node + 1], e = rowptr[2 * node + 2];
  int c0 = lane, c1 = lane + 64, c2 = lane + 128;
  bool ok2 = (c2 < H);
  float a0 = 0.f, a1 = 0.f, a2 = 0.f;
  for (int p = s; p < mid; p++) {
    const u32* row = npk + (size_t)colbuf[p] * 160;
    a0 += upk(row[c0]); a1 += upk(row[c1]); if (ok2) a2 += upk(row[c2]);
  }
  float b0 = 0.f, b1 = 0.f, b2 = 0.f;
  for (int p = mid; p < e; p++) {
    const u32* row = npk + (size_t)colbuf[p] * 160;
    b0 += upk(row[c0]); b1 += upk(row[c1]); if (ok2) b2 += upk(row[c2]);
  }
  u16* oh = Sh + (size_t)node * 320;
  u16* ol = Sl + (size_t)node * 320;
  u16 h;
  h = f2bf_rn(a0); oh[c0] = h; ol[c0] = f2bf_rn(a0 - bf2f(h));
  h = f2bf_rn(a1); oh[c1] = h; ol[c1] = f2bf_rn(a1 - bf2f(h));
  if (ok2) { h = f2bf_rn(a2); oh[c2] = h; ol[c2] = f2bf_rn(a2 - bf2f(h)); }
  h = f2bf_rn(b0); oh[160 + c0] = h; ol[160 + c0] = f2bf_rn(b0 - bf2f(h));
  h = f2bf_rn(b1); oh[160 + c1] = h; ol[160 + c1] = f2bf_rn(b1 - bf2f(h));
  if (ok2) { h = f2bf_rn(b2); oh[160 + c2] = h; ol[160 + c2] = f2bf_rn(b2 - bf2f(h)); }
}

// ---------------- fused GRU GEMM: C[NN x 640] = X[NN x 480] @ B'^T, epilogue gates ----
// 128x128 tile, 128 thr / 2 waves; wave w: ALL 8 m-tiles x 4 n-tiles
// (cols [w*64,+64) = one c-chunk x 4 gates, in-register combine).
// XCD swizzle (confirmed R7: FETCH 278->68 MB): bid -> xcd=bid&7, ccb=(bid>>3)%5,
// r0b=((bid>>3)/5)*8+xcd -> the 5 col-blocks sharing an A-slab land on ONE XCD.
// R8 change: BK=64 stages (5x S hi/lo, 2x packed-node, 1x BK=32 tail) -> 8 stages
// instead of 15 -> 2x MFMA per barrier drain (drain was 78% of time at BK=32).
// LDS 64KB/block -> 2 blocks/CU. All LDS reads 2-way-conflict max (free).
__global__ __launch_bounds__(128) void gru_gemm_kernel(
    const u16* __restrict__ Sh, const u16* __restrict__ Sl,
    const u32* __restrict__ npkc,
    const u16* __restrict__ Bh, const u16* __restrict__ Bl,
    const float* __restrict__ coefs, const int* __restrict__ rowptr,
    u32* __restrict__ npkn) {
  __shared__ char Abuf[32768];   // P1: [0,16K)=hi,[16K,32K)=lo ; P2: packed u32 tile
  __shared__ char Bbuf[32768];   // [0,16K)=hi, [16K,32K)=lo
  const int bid = blockIdx.x;
  const int xcd = bid & 7;
  const int rest = bid >> 3;
  const int ccb = rest % 5;
  const int r0b = (rest / 5) * 8 + xcd;
  if (r0b >= NRB) return;
  const int r0 = r0b * 128;
  const int tid = threadIdx.x;
  const int w = tid >> 6, l = tid & 63;
  const int m = l & 15, quad = l >> 4;

  float4v acc[8][4];
  #pragma unroll
  for (int mt = 0; mt < 8; mt++)
    #pragma unroll
    for (int j = 0; j < 4; j++) acc[mt][j] = (float4v){0.f, 0.f, 0.f, 0.f};

  // ---- Phase 1: 5 stages of BK=64 over S (k 0..320), A/B rows = 128B (8 chunks) ----
  #pragma unroll 1
  for (int st = 0; st < 5; st++) {
    int ko = st * 64;
    #pragma unroll
    for (int i = 0; i < 8; i++) {
      int cl = i * 128 + tid;                    // [0,1024)
      int row = cl >> 3;
      int q = (cl & 7) ^ (row & 7);
      int rg = min(r0 + row, NN - 1);
      size_t go = (size_t)rg * 320 + ko + q * 8;
      int lb = i * 2048 + w * 1024;
      async16(Sh + go, Abuf + lb);
      async16(Sl + go, Abuf + 16384 + lb);
      size_t gb = (size_t)(ccb * 128 + row) * KB + ko + q * 8;
      async16(Bh + gb, Bbuf + lb);
      async16(Bl + gb, Bbuf + 16384 + lb);
    }
    __syncthreads();
    #pragma unroll
    for (int t = 0; t < 2; t++) {
      short8 bh[4], bl[4];
      #pragma unroll
      for (int j = 0; j < 4; j++) {
        int br = w * 64 + j * 16 + m;
        int bd = br * 128 + (((t * 4 + quad) ^ (br & 7)) * 16);
        bh[j] = *(const short8*)(Bbuf + bd);
        bl[j] = *(const short8*)(Bbuf + 16384 + bd);
      }
      #pragma unroll
      for (int mt = 0; mt < 8; mt++) {
        int r = mt * 16 + m;
        int ad = r * 128 + (((t * 4 + quad) ^ (r & 7)) * 16);
        short8 ah = *(const short8*)(Abuf + ad);
        short8 al = *(const short8*)(Abuf + 16384 + ad);
        #pragma unroll
        for (int j = 0; j < 4; j++) {
          acc[mt][j] = __builtin_amdgcn_mfma_f32_16x16x32_bf16(ah, bh[j], acc[mt][j], 0, 0, 0);
          acc[mt][j] = __builtin_amdgcn_mfma_f32_16x16x32_bf16(ah, bl[j], acc[mt][j], 0, 0, 0);
          acc[mt][j] = __builtin_amdgcn_mfma_f32_16x16x32_bf16(al, bh[j], acc[mt][j], 0, 0, 0);
        }
      }
    }
    __syncthreads();
  }

  // ---- Phase 2: 2 stages BK=64 over packed nodes (k 320..448) ----
  // A rows = 64 u32 = 256B (16 chunks); B rows = 128B (8 chunks)
  #pragma unroll 1
  for (int st = 0; st < 2; st++) {
    int ko = st * 64;                            // npk element offset
    #pragma unroll
    for (int i = 0; i < 16; i++) {
      int cl = i * 128 + tid;                    // [0,2048)
      int row = cl >> 4;
      int q = (cl & 15) ^ (row & 15);
      int rg = min(r0 + row, NN - 1);
      async16(npkc + (size_t)rg * 160 + ko + q * 4, Abuf + i * 2048 + w * 1024);
    }
    #pragma unroll
    for (int i = 0; i < 8; i++) {
      int cl = i * 128 + tid;
      int row = cl >> 3;
      int q = (cl & 7) ^ (row & 7);
      size_t gb = (size_t)(ccb * 128 + row) * KB + 320 + st * 64 + q * 8;
      int lb = i * 2048 + w * 1024;
      async16(Bh + gb, Bbuf + lb);
      async16(Bl + gb, Bbuf + 16384 + lb);
    }
    __syncthreads();
    #pragma unroll
    for (int t = 0; t < 2; t++) {
      short8 bh[4], bl[4];
      #pragma unroll
      for (int j = 0; j < 4; j++) {
        int br = w * 64 + j * 16 + m;
        int bd = br * 128 + (((t * 4 + quad) ^ (br & 7)) * 16);
        bh[j] = *(const short8*)(Bbuf + bd);
        bl[j] = *(const short8*)(Bbuf + 16384 + bd);
      }
      #pragma unroll
      for (int mt = 0; mt < 8; mt++) {
        int r = mt * 16 + m;
        int g0 = t * 8 + quad * 2;
        uint4v p0 = *(const uint4v*)(Abuf + r * 256 + ((g0 ^ (r & 15)) * 16));
        uint4v p1 = *(const uint4v*)(Abuf + r * 256 + (((g0 + 1) ^ (r & 15)) * 16));
        u32 uu[8] = {p0.x, p0.y, p0.z, p0.w, p1.x, p1.y, p1.z, p1.w};
        short8 ah, al;
        #pragma unroll
        for (int e2 = 0; e2 < 8; e2++) {
          ah[e2] = (short)(uu[e2] & 0xffffu);
          al[e2] = (short)(uu[e2] >> 16);
        }
        #pragma unroll
        for (int j = 0; j < 4; j++) {
          acc[mt][j] = __builtin_amdgcn_mfma_f32_16x16x32_bf16(ah, bh[j], acc[mt][j], 0, 0, 0);
          acc[mt][j] = __builtin_amdgcn_mfma_f32_16x16x32_bf16(ah, bl[j], acc[mt][j], 0, 0, 0);
          acc[mt][j] = __builtin_amdgcn_mfma_f32_16x16x32_bf16(al, bh[j], acc[mt][j], 0, 0, 0);
        }
      }
    }
    __syncthreads();
  }

  // ---- Tail: BK=32 (k 448..480 = npk cols 128..160) ----
  {
    #pragma unroll
    for (int i = 0; i < 8; i++) {
      int cl = i * 128 + tid;                    // [0,1024)
      int row = cl >> 3;
      int q = (cl & 7) ^ (row & 7);
      int rg = min(r0 + row, NN - 1);
      async16(npkc + (size_t)rg * 160 + 128 + q * 4, Abuf + i * 2048 + w * 1024);
    }
    #pragma unroll
    for (int i = 0; i < 4; i++) {
      int cl = i * 128 + tid;                    // [0,512)
      int row = cl >> 2;
      int q = (cl & 3) ^ ((row >> 1) & 3);
      size_t gb = (size_t)(ccb * 128 + row) * KB + 448 + q * 8;
      int lb = i * 2048 + w * 1024;
      async16(Bh + gb, Bbuf + lb);
      async16(Bl + gb, Bbuf + 16384 + lb);
    }
    __syncthreads();
    short8 bh[4], bl[4];
    #pragma unroll
    for (int j = 0; j < 4; j++) {
      int br = w * 64 + j * 16 + m;
      int bd = br * 64 + ((quad ^ ((br >> 1) & 3)) * 16);
      bh[j] = *(const short8*)(Bbuf + bd);
      bl[j] = *(const short8*)(Bbuf + 16384 + bd);
    }
    #pragma unroll
    for (int mt = 0; mt < 8; mt++) {
      int r = mt * 16 + m;
      int g0 = quad * 2;
      uint4v p0 = *(const uint4v*)(Abuf + r * 128 + ((g0 ^ (r & 7)) * 16));
      uint4v p1 = *(const uint4v*)(Abuf + r * 128 + (((g0 + 1) ^ (r & 7)) * 16));
      u32 uu[8] = {p0.x, p0.y, p0.z, p0.w, p1.x, p1.y, p1.z, p1.w};
      short8 ah, al;
      #pragma unroll
      for (int e2 = 0; e2 < 8; e2++) {
        ah[e2] = (short)(uu[e2] & 0xffffu);
        al[e2] = (short)(uu[e2] >> 16);
      }
      #pragma unroll
      for (int j = 0; j < 4; j++) {
        acc[mt][j] = __builtin_amdgcn_mfma_f32_16x16x32_bf16(ah, bh[j], acc[mt][j], 0, 0, 0);
        acc[mt][j] = __builtin_amdgcn_mfma_f32_16x16x32_bf16(ah, bl[j], acc[mt][j], 0, 0, 0);
        acc[mt][j] = __builtin_amdgcn_mfma_f32_16x16x32_bf16(al, bh[j], acc[mt][j], 0, 0, 0);
      }
    }
  }

  // ---- epilogue: gate math; wave w handles c-chunk cc=2*ccb+w, tiles j = gate ----
  int c = (2 * ccb + w) * 16 + m;
  if (c >= H) return;
  float u0r = coefs[c],            u0z = coefs[160 + c],
        u0n = coefs[320 + c];
  float u1r = coefs[VC + c],       u1z = coefs[VC + 160 + c],
        u1n = coefs[VC + 320 + c];
  float bsr = coefs[2 * VC + c],   bsz = coefs[2 * VC + 160 + c],
        bsn = coefs[2 * VC + 320 + c], bsh = coefs[2 * VC + 480 + c];
  #pragma unroll
  for (int mt = 0; mt < 8; mt++) {
    #pragma unroll
    for (int i = 0; i < 4; i++) {
      int row = r0 + mt * 16 + quad * 4 + i;
      if (row >= NN) continue;
      float d0 = (float)(rowptr[2 * row + 1] - rowptr[2 * row]);
      float d1 = (float)(rowptr[2 * row + 2] - rowptr[2 * row + 1]);
      float pr = acc[mt][0][i] + d0 * u0r + d1 * u1r + bsr;
      float pz = acc[mt][1][i] + d0 * u0z + d1 * u1z + bsz;
      float pn = acc[mt][2][i] + d0 * u0n + d1 * u1n + bsn;
      float ph = acc[mt][3][i] + bsh;
      float r_g = 1.f / (1.f + __expf(-pr));
      float z_g = 1.f / (1.f + __expf(-pz));
      float narg = pn + r_g * ph;
      float e2 = __expf(2.f * narg);
      float n_g = 1.f - 2.f / (e2 + 1.f);       // tanh, inf-safe
      float h = upk(npkc[(size_t)row * 160 + c]);
      npkn[(size_t)row * 160 + c] = packf((1.f - z_g) * n_g + z_g * h);
    }
  }
}

// ---------------- readout ----------------
__global__ __launch_bounds__(192) void segsum_kernel(const u32* __restrict__ npk,
                                                     const int* __restrict__ gstart,
                                                     float* __restrict__ gsum) {
  int g = blockIdx.x, chunk = blockIdx.y;
  int c = threadIdx.x;
  if (c >= H) return;
  int s = gstart[g], e = gstart[g + 1];
  int len = e - s;
  if (len <= 0) return;
  int per = (len + 3) / 4;
  int rs = s + chunk * per;
  int re = min(e, rs + per);
  if (rs >= re) return;
  float acc = 0.f;
  for (int r = rs; r < re; r++) acc += upk(npk[(size_t)r * 160 + c]);
  atomicAdd(&gsum[g * H + c], acc);
}

__global__ __launch_bounds__(256) void head_kernel(
    const float* __restrict__ gsum, const float* __restrict__ pt,
    const float* __restrict__ fc1_w, const float* __restrict__ fc1_b,
    const float* __restrict__ fc2_w, const float* __restrict__ fc2_b,
    const float* __restrict__ fcL_w, const float* __restrict__ fcL_b,
    float* __restrict__ out) {
  __shared__ float bufA[NG * 151];
  __shared__ float X1[NG * 80];
  int tid = threadIdx.x;
  for (int e = tid; e < NG * 151; e += 256) {
    int row = e / 151, c = e % 151;
    float v;
    if (c < H) { float g = gsum[row * H + c]; v = (g > 1.f) ? logf(g) : 0.f; }
    else v = pt[row];
    bufA[e] = v;
  }
  __syncthreads();
  for (int e = tid; e < NG * 80; e += 256) {
    int row = e / 80, o = e % 80;
    float acc = fc1_b[o];
    for (int k = 0; k < 151; k++) acc += bufA[row * 151 + k] * fc1_w[o * 151 + k];
    X1[e] = (acc > 0.f) ? acc : 0.01f * acc;
  }
  __syncthreads();
  for (int e = tid; e < NG * 80; e += 256) {
    int row = e / 80, o = e % 80;
    float acc = fc2_b[o];
    for (int k = 0; k < 80; k++) acc += X1[row * 80 + k] * fc2_w[o * 80 + k];
    bufA[e] = (acc > 0.f) ? acc : 0.01f * acc;
  }
  __syncthreads();
  for (int e = tid; e < NG * 10; e += 256) {
    int row = e / 10, o = e % 10;
    float acc = fcL_b[o];
    for (int k = 0; k < 80; k++) acc += bufA[row * 80 + k] * fcL_w[o * 80 + k];
    out[e] = acc;
  }
}

extern "C" void kernel_launch(void* const* d_in, const int* in_sizes, int n_in,
                              void* d_out, int out_size, void* d_ws, size_t ws_size,
                              hipStream_t stream) {
  const float* nodes_in = (const float*)d_in[0];
  const float* problem_type = (const float*)d_in[1];
  const float* edge_W = (const float*)d_in[2];
  const float* edge_b = (const float*)d_in[3];
  const float* w_ih = (const float*)d_in[4];
  const float* w_hh = (const float*)d_in[5];
  const float* b_ih = (const float*)d_in[6];
  const float* b_hh = (const float*)d_in[7];
  const float* fc1_w = (const float*)d_in[8];
  const float* fc1_b = (const float*)d_in[9];
  const float* fc2_w = (const float*)d_in[10];
  const float* fc2_b = (const float*)d_in[11];
  const float* fcL_w = (const float*)d_in[12];
  const float* fcL_b = (const float*)d_in[13];
  const int* edges = (const int*)d_in[14];
  const int* graph_ids = (const int*)d_in[15];

  char* ws = (char*)d_ws;
  size_t off = 0;
  auto alloc = [&](size_t bytes) -> void* {
    void* p = ws + off;
    off = (off + bytes + 255) & ~(size_t)255;
    return p;
  };
  u32* npkA     = (u32*)alloc((size_t)NN * 160 * 4);           // 32 MB
  u32* npkB     = (u32*)alloc((size_t)NN * 160 * 4);           // 32 MB
  u16* Sh       = (u16*)alloc((size_t)NN * 320 * 2);           // 32 MB
  u16* Sl       = (u16*)alloc((size_t)NN * 320 * 2);           // 32 MB
  u16* Bh       = (u16*)alloc((size_t)VC * KB * 2);            // 0.61 MB
  u16* Bl       = (u16*)alloc((size_t)VC * KB * 2);            // 0.61 MB
  float* coefs  = (float*)alloc(3 * VC * 4);
  int* rowptr   = (int*)alloc((2 * NN + 1) * 4);
  int* cursor   = (int*)alloc(2 * NN * 4);
  u16* colbuf   = (u16*)alloc(2ull * NE * 2);                  // 1.6 MB
  int* bsum     = (int*)alloc(128 * 4);
  int* boff     = (int*)alloc(128 * 4);
  int* gstart   = (int*)alloc((NG + 1) * 4);
  float* gsum   = (float*)alloc((size_t)NG * H * 4);

  const int n2 = 2 * NN;                 // 100000 counters
  const int nb = (n2 + 1023) / 1024;     // 98 scan blocks

  // ---- one-time setup ----
  hipMemsetAsync(cursor, 0, n2 * 4, stream);
  hist_kernel<<<(2 * NE + 255) / 256, 256, 0, stream>>>(edges, cursor);
  scan1_kernel<<<nb, 1024, 0, stream>>>(cursor, rowptr, bsum, n2);
  scan2_kernel<<<1, 128, 0, stream>>>(bsum, boff, nb);
  scan3_kernel<<<(n2 + 255) / 256, 256, 0, stream>>>(rowptr, boff, n2);
  total_kernel<<<1, 64, 0, stream>>>(rowptr, boff, n2, nb);
  copy_int_kernel<<<(n2 + 255) / 256, 256, 0, stream>>>(rowptr, cursor, n2);
  fill_kernel<<<(2 * NE + 255) / 256, 256, 0, stream>>>(edges, cursor, colbuf);
  bounds_kernel<<<1, 128, 0, stream>>>(graph_ids, gstart);
  build_B_kernel<<<(VC * KB + 255) / 256, 256, 0, stream>>>(w_ih, w_hh, edge_W, Bh, Bl);
  build_coef_kernel<<<(VC + 255) / 256, 256, 0, stream>>>(w_ih, edge_b, b_ih, b_hh, coefs);
  init_nodes_kernel<<<(NN * 160 + 255) / 256, 256, 0, stream>>>(nodes_in, npkA, npkB);
  pad_S_kernel<<<(NN * 20 + 255) / 256, 256, 0, stream>>>(Sh, Sl);

  // ---- 5 message-passing iterations (packed nodes ping-pong) ----
  const int ngrp = (NRB + 7) / 8;        // 49 groups of 8 row-blocks
  u32* nbuf[2] = {npkA, npkB};
  for (int pass = 0; pass < NPASS; pass++) {
    u32* cur = nbuf[pass & 1];
    u32* nxt = nbuf[1 - (pass & 1)];
    gather_kernel<<<(NN * 64 + 255) / 256, 256, 0, stream>>>(cur, rowptr, colbuf, Sh, Sl);
    gru_gemm_kernel<<<ngrp * 5 * 8, 128, 0, stream>>>(
        Sh, Sl, cur, Bh, Bl, coefs, rowptr, nxt);
  }
  u32* fin = nbuf[NPASS & 1];

  // ---- readout ----
  hipMemsetAsync(gsum, 0, (size_t)NG * H * 4, stream);
  segsum_kernel<<<dim3(NG, 4), 192, 0, stream>>>(fin, gstart, gsum);
  head_kernel<<<1, 256, 0, stream>>>(gsum, problem_type, fc1_w, fc1_b, fc2_w, fc2_b,
                                     fcL_w, fcL_b, (float*)d_out);
}

// Round 9
// 1385.506 us; speedup vs baseline: 1.9892x; 1.1636x over previous
//
#include <hip/hip_runtime.h>
#include <stdint.h>

#define NN 50000
#define H 150
#define NE 400000
#define NG 64
#define NPASS 5
#define KB 480          // GRU GEMM K: [S0(160) | S1(160) | nodes(160)]
#define VC 640          // 40 col-tiles: v = cc*64 + g*16 + cl, c = cc*16+cl
#define NRB 391         // row blocks of 128

typedef unsigned short u16;
typedef unsigned int u32;
typedef __attribute__((ext_vector_type(8))) short short8;
typedef __attribute__((ext_vector_type(4))) float float4v;
typedef __attribute__((ext_vector_type(4))) u32 uint4v;

// ---------------- helpers ----------------
__device__ __forceinline__ u16 f2bf_rn(float x) {
  union { float f; u32 u; } v; v.f = x;
  u32 r = v.u + 0x7fffu + ((v.u >> 16) & 1u);
  return (u16)(r >> 16);
}
__device__ __forceinline__ float bf2f(u16 h) {
  union { u32 u; float f; } v; v.u = ((u32)h) << 16;
  return v.f;
}
// packed node word: low16 = hi bf16, high16 = lo bf16; value = hi + lo
__device__ __forceinline__ u32 packf(float v) {
  u16 hi = f2bf_rn(v);
  u16 lo = f2bf_rn(v - bf2f(hi));
  return (u32)hi | ((u32)lo << 16);
}
__device__ __forceinline__ float upk(u32 u) {
  union { u32 u; float f; } a, b;
  a.u = u << 16; b.u = u & 0xffff0000u;
  return a.f + b.f;
}
// async global->LDS, 16B per lane; lds dest must be wave-uniform base
__device__ __forceinline__ void async16(const void* g, void* l) {
  __builtin_amdgcn_global_load_lds(
      (const __attribute__((address_space(1))) unsigned int*)(uintptr_t)g,
      (__attribute__((address_space(3))) unsigned int*)(uint32_t)(uintptr_t)l,
      16, 0, 0);
}

// ---------------- CSR build (key = node*2 + set) ----------------
__global__ void hist_kernel(const int* __restrict__ edges, int* __restrict__ cnt) {
  int id = blockIdx.x * 256 + threadIdx.x;
  if (id >= 2 * NE) return;
  int dst = edges[id * 2];
  int set = id / NE;
  atomicAdd(&cnt[dst * 2 + set], 1);
}

__global__ __launch_bounds__(1024) void scan1_kernel(const int* __restrict__ cnt,
                                                     int* __restrict__ rowptr,
                                                     int* __restrict__ bsum, int n) {
  __shared__ int sd[1024];
  int t = threadIdx.x;
  int idx = blockIdx.x * 1024 + t;
  int v = (idx < n) ? cnt[idx] : 0;
  sd[t] = v;
  __syncthreads();
  for (int off = 1; off < 1024; off <<= 1) {
    int add = (t >= off) ? sd[t - off] : 0;
    __syncthreads();
    sd[t] += add;
    __syncthreads();
  }
  if (idx < n) rowptr[idx] = sd[t] - v;     // block-local exclusive
  if (t == 1023) bsum[blockIdx.x] = sd[1023];
}

__global__ __launch_bounds__(128) void scan2_kernel(const int* __restrict__ bsum,
                                                    int* __restrict__ boff, int nb) {
  __shared__ int sd[128];
  int t = threadIdx.x;
  int v = (t < nb) ? bsum[t] : 0;
  sd[t] = v;
  __syncthreads();
  for (int off = 1; off < 128; off <<= 1) {
    int add = (t >= off) ? sd[t - off] : 0;
    __syncthreads();
    sd[t] += add;
    __syncthreads();
  }
  boff[t] = sd[t] - v;                       // exclusive; boff[nb] = total
}

__global__ void scan3_kernel(int* __restrict__ rowptr, const int* __restrict__ boff, int n) {
  int idx = blockIdx.x * 256 + threadIdx.x;
  if (idx < n) rowptr[idx] += boff[idx >> 10];
}

__global__ void total_kernel(int* __restrict__ rowptr, const int* __restrict__ boff, int n, int nb) {
  if (threadIdx.x == 0 && blockIdx.x == 0) rowptr[n] = boff[nb];
}

__global__ void copy_int_kernel(const int* __restrict__ a, int* __restrict__ b, int n) {
  int id = blockIdx.x * 256 + threadIdx.x;
  if (id < n) b[id] = a[id];
}

__global__ void fill_kernel(const int* __restrict__ edges, int* __restrict__ cursor,
                            u16* __restrict__ colbuf) {
  int id = blockIdx.x * 256 + threadIdx.x;
  if (id >= 2 * NE) return;
  int dst = edges[id * 2];
  int src = edges[id * 2 + 1];
  int set = id / NE;
  int pos = atomicAdd(&cursor[dst * 2 + set], 1);
  colbuf[pos] = (u16)src;
}

__global__ void bounds_kernel(const int* __restrict__ gids, int* __restrict__ gstart) {
  int g = threadIdx.x;
  if (g > NG) return;
  int lo = 0, hi = NN;
  while (lo < hi) { int m = (lo + hi) >> 1; if (gids[m] < g) lo = m + 1; else hi = m; }
  gstart[g] = lo;
}

// ---------------- one-time weight prep ----------------
// B'[v][k], v in [0,640): g=(v>>4)&3, c=(v>>6)*16+(v&15)
// k<160: (W_ihg @ W0)[c][k]      (g<3; g3=0)
// 160<=k<320: (W_ihg @ W1)[c][k-160]
// 320<=k<480: g0: w_hh[c][kk], g1: w_hh[150+c][kk], g3: w_hh[300+c][kk], g2: 0
__global__ void build_B_kernel(const float* __restrict__ wih, const float* __restrict__ whh,
                               const float* __restrict__ eW,
                               u16* __restrict__ Bh, u16* __restrict__ Bl) {
  int id = blockIdx.x * 256 + threadIdx.x;
  if (id >= VC * KB) return;
  int v = id / KB, k = id % KB;
  int g = (v >> 4) & 3, c = (v >> 6) * 16 + (v & 15);
  int seg = k / 160, kk = k % 160;
  float val = 0.f;
  if (c < H && kk < H) {
    if (seg < 2) {
      if (g < 3) {
        const float* wr = wih + (size_t)(g * H + c) * H;
        const float* wc = eW + (size_t)seg * H * H + kk;
        float acc = 0.f;
        for (int t = 0; t < H; t++) acc += wr[t] * wc[(size_t)t * H];
        val = acc;
      }
    } else {
      if (g == 0) val = whh[(size_t)c * H + kk];
      else if (g == 1) val = whh[(size_t)(H + c) * H + kk];
      else if (g == 3) val = whh[(size_t)(2 * H + c) * H + kk];
    }
  }
  u16 h = f2bf_rn(val);
  Bh[id] = h;
  Bl[id] = f2bf_rn(val - bf2f(h));
}

// coefs[0][g*160+c] = W_ihg @ b0 (deg0 coef), coefs[1] = W_ihg @ b1, coefs[2] = gate bias
__global__ void build_coef_kernel(const float* __restrict__ wih,
                                  const float* __restrict__ eb,
                                  const float* __restrict__ bih, const float* __restrict__ bhh,
                                  float* __restrict__ coefs) {
  int id = threadIdx.x + blockIdx.x * 256;
  if (id >= VC) return;
  int g = id / 160, c = id % 160;
  float u0 = 0.f, u1 = 0.f, bs = 0.f;
  if (c < H) {
    if (g < 3) {
      const float* wr = wih + (size_t)(g * H + c) * H;
      for (int t = 0; t < H; t++) { u0 += wr[t] * eb[t]; u1 += wr[t] * eb[H + t]; }
    }
    if (g == 0) bs = bih[c] + bhh[c];
    else if (g == 1) bs = bih[H + c] + bhh[H + c];
    else if (g == 2) bs = bih[2 * H + c];
    else bs = bhh[2 * H + c];
  }
  coefs[id] = u0;
  coefs[VC + id] = u1;
  coefs[2 * VC + id] = bs;
}

// pack input nodes into npkA; zero pad cols of both buffers
__global__ void init_nodes_kernel(const float* __restrict__ nin,
                                  u32* __restrict__ npkA, u32* __restrict__ npkB) {
  int id = blockIdx.x * 256 + threadIdx.x;
  if (id >= NN * 160) return;
  int r = id / 160, c = id % 160;
  if (c < H) {
    npkA[id] = packf(nin[(size_t)r * H + c]);
  } else {
    npkA[id] = 0;
    npkB[id] = 0;
  }
}

__global__ void pad_S_kernel(u16* __restrict__ Sh, u16* __restrict__ Sl) {
  int id = blockIdx.x * 256 + threadIdx.x;
  if (id >= NN * 20) return;
  int r = id / 20, rem = id % 20;
  int set = rem / 10, t = rem % 10;
  size_t off = (size_t)r * 320 + set * 160 + H + t;
  Sh[off] = 0; Sl[off] = 0;
}

// ---------------- gather: S[n][set*160+c] = sum of raw node rows ----------------
// 2-edge manual unroll: doubles outstanding loads in the latency-bound degree loop.
__global__ __launch_bounds__(256) void gather_kernel(
    const u32* __restrict__ npk, const int* __restrict__ rowptr,
    const u16* __restrict__ colbuf, u16* __restrict__ Sh, u16* __restrict__ Sl) {
  int gtid = blockIdx.x * 256 + threadIdx.x;
  int node = gtid >> 6;
  int lane = gtid & 63;
  if (node >= NN) return;
  int s = rowptr[2 * node], mid = rowptr[2 * node + 1], e = rowptr[2 * node + 2];
  int c0 = lane, c1 = lane + 64, c2 = lane + 128;
  bool ok2 = (c2 < H);
  float a0 = 0.f, a1 = 0.f, a2 = 0.f;
  int p = s;
  for (; p + 1 < mid; p += 2) {
    const u32* rA = npk + (size_t)colbuf[p] * 160;
    const u32* rB = npk + (size_t)colbuf[p + 1] * 160;
    u32 xa0 = rA[c0], xa1 = rA[c1];
    u32 xb0 = rB[c0], xb1 = rB[c1];
    u32 xa2 = 0, xb2 = 0;
    if (ok2) { xa2 = rA[c2]; xb2 = rB[c2]; }
    a0 += upk(xa0) + upk(xb0);
    a1 += upk(xa1) + upk(xb1);
    if (ok2) a2 += upk(xa2) + upk(xb2);
  }
  if (p < mid) {
    const u32* rA = npk + (size_t)colbuf[p] * 160;
    a0 += upk(rA[c0]); a1 += upk(rA[c1]); if (ok2) a2 += upk(rA[c2]);
  }
  float b0 = 0.f, b1 = 0.f, b2 = 0.f;
  p = mid;
  for (; p + 1 < e; p += 2) {
    const u32* rA = npk + (size_t)colbuf[p] * 160;
    const u32* rB = npk + (size_t)colbuf[p + 1] * 160;
    u32 xa0 = rA[c0], xa1 = rA[c1];
    u32 xb0 = rB[c0], xb1 = rB[c1];
    u32 xa2 = 0, xb2 = 0;
    if (ok2) { xa2 = rA[c2]; xb2 = rB[c2]; }
    b0 += upk(xa0) + upk(xb0);
    b1 += upk(xa1) + upk(xb1);
    if (ok2) b2 += upk(xa2) + upk(xb2);
  }
  if (p < e) {
    const u32* rA = npk + (size_t)colbuf[p] * 160;
    b0 += upk(rA[c0]); b1 += upk(rA[c1]); if (ok2) b2 += upk(rA[c2]);
  }
  u16* oh = Sh + (size_t)node * 320;
  u16* ol = Sl + (size_t)node * 320;
  u16 h;
  h = f2bf_rn(a0); oh[c0] = h; ol[c0] = f2bf_rn(a0 - bf2f(h));
  h = f2bf_rn(a1); oh[c1] = h; ol[c1] = f2bf_rn(a1 - bf2f(h));
  if (ok2) { h = f2bf_rn(a2); oh[c2] = h; ol[c2] = f2bf_rn(a2 - bf2f(h)); }
  h = f2bf_rn(b0); oh[160 + c0] = h; ol[160 + c0] = f2bf_rn(b0 - bf2f(h));
  h = f2bf_rn(b1); oh[160 + c1] = h; ol[160 + c1] = f2bf_rn(b1 - bf2f(h));
  if (ok2) { h = f2bf_rn(b2); oh[160 + c2] = h; ol[160 + c2] = f2bf_rn(b2 - bf2f(h)); }
}

// ---------------- fused GRU GEMM: C[NN x 640] = X[NN x 480] @ B'^T, epilogue gates ----
// R9: R6 structure WITHOUT the register cap (R6's spill came from __launch_bounds__(256,3)):
// 128x128 tile, 256 thr / 4 waves; wave w: rows [(w&1)*64,+64) (4 mt) x cols
// [(w>>1)*64,+64) (4 gate-tiles of one c-chunk -> in-register gate combine).
// acc = 64 VGPR/wave -> VGPR ~160 -> ~3 waves/SIMD resident, drains overlap.
// BK=32 (m132 lesson: bigger BK loses), 32KB LDS. XCD swizzle (R7-proven).
// Phase 2 A = packed u32 nodes, shift-unpack.
__global__ __launch_bounds__(256) void gru_gemm_kernel(
    const u16* __restrict__ Sh, const u16* __restrict__ Sl,
    const u32* __restrict__ npkc,
    const u16* __restrict__ Bh, const u16* __restrict__ Bl,
    const float* __restrict__ coefs, const int* __restrict__ rowptr,
    u32* __restrict__ npkn) {
  __shared__ char Abuf[16384];   // p1: [0,8K)=hi,[8K,16K)=lo ; p2: packed u32 tile
  __shared__ char Bbuf[16384];   // [0,8K)=hi, [8K,16K)=lo
  const int bid = blockIdx.x;
  const int xcd = bid & 7;
  const int rest = bid >> 3;
  const int ccb = rest % 5;
  const int r0b = (rest / 5) * 8 + xcd;
  if (r0b >= NRB) return;
  const int r0 = r0b * 128;
  const int tid = threadIdx.x;
  const int w = tid >> 6, l = tid & 63;
  const int m = l & 15, quad = l >> 4;
  const int mrow0 = (w & 1) * 64;
  const int nco0 = (w >> 1) * 64;

  float4v acc[4][4];
  #pragma unroll
  for (int mt = 0; mt < 4; mt++)
    #pragma unroll
    for (int j = 0; j < 4; j++) acc[mt][j] = (float4v){0.f, 0.f, 0.f, 0.f};

  // ---- K phase 1: S half (bf16 hi/lo), kt 0..9 ----
  #pragma unroll 1
  for (int kt = 0; kt < 10; kt++) {
    int koff = kt * 32;
    #pragma unroll
    for (int i = 0; i < 2; i++) {
      int cl = i * 256 + tid;                     // [0,512)
      int row = cl >> 2;
      int q = (cl & 3) ^ ((row >> 1) & 3);
      int rg = min(r0 + row, NN - 1);
      size_t go = (size_t)rg * 320 + koff + q * 8;
      int lb = i * 4096 + w * 1024;
      async16(Sh + go, Abuf + lb);
      async16(Sl + go, Abuf + 8192 + lb);
      size_t gb = (size_t)(ccb * 128 + row) * KB + koff + q * 8;
      async16(Bh + gb, Bbuf + lb);
      async16(Bl + gb, Bbuf + 8192 + lb);
    }
    __syncthreads();
    short8 bh[4], bl[4];
    #pragma unroll
    for (int j = 0; j < 4; j++) {
      int br = nco0 + j * 16 + m;
      int bd = br * 64 + ((quad ^ ((br >> 1) & 3)) * 16);
      bh[j] = *(const short8*)(Bbuf + bd);
      bl[j] = *(const short8*)(Bbuf + 8192 + bd);
    }
    #pragma unroll
    for (int mt = 0; mt < 4; mt++) {
      int r = mrow0 + mt * 16 + m;
      int ad = r * 64 + ((quad ^ ((r >> 1) & 3)) * 16);
      short8 ah = *(const short8*)(Abuf + ad);
      short8 al = *(const short8*)(Abuf + 8192 + ad);
      #pragma unroll
      for (int j = 0; j < 4; j++) {
        acc[mt][j] = __builtin_amdgcn_mfma_f32_16x16x32_bf16(ah, bh[j], acc[mt][j], 0, 0, 0);
        acc[mt][j] = __builtin_amdgcn_mfma_f32_16x16x32_bf16(ah, bl[j], acc[mt][j], 0, 0, 0);
        acc[mt][j] = __builtin_amdgcn_mfma_f32_16x16x32_bf16(al, bh[j], acc[mt][j], 0, 0, 0);
      }
    }
    __syncthreads();
  }

  // ---- K phase 2: nodes half (packed u32, shift-unpack), kt 10..14 ----
  #pragma unroll 1
  for (int kt = 0; kt < 5; kt++) {
    int koff = kt * 32;
    #pragma unroll
    for (int i = 0; i < 4; i++) {
      int cl = i * 256 + tid;                     // [0,1024)
      int row = cl >> 3;
      int q = (cl & 7) ^ (row & 7);
      int rg = min(r0 + row, NN - 1);
      async16(npkc + (size_t)rg * 160 + koff + q * 4, Abuf + i * 4096 + w * 1024);
    }
    #pragma unroll
    for (int i = 0; i < 2; i++) {
      int cl = i * 256 + tid;
      int row = cl >> 2;
      int q = (cl & 3) ^ ((row >> 1) & 3);
      size_t gb = (size_t)(ccb * 128 + row) * KB + 320 + koff + q * 8;
      int lb = i * 4096 + w * 1024;
      async16(Bh + gb, Bbuf + lb);
      async16(Bl + gb, Bbuf + 8192 + lb);
    }
    __syncthreads();
    short8 bh[4], bl[4];
    #pragma unroll
    for (int j = 0; j < 4; j++) {
      int br = nco0 + j * 16 + m;
      int bd = br * 64 + ((quad ^ ((br >> 1) & 3)) * 16);
      bh[j] = *(const short8*)(Bbuf + bd);
      bl[j] = *(const short8*)(Bbuf + 8192 + bd);
    }
    #pragma unroll
    for (int mt = 0; mt < 4; mt++) {
      int r = mrow0 + mt * 16 + m;
      uint4v p0 = *(const uint4v*)(Abuf + r * 128 + (((2 * quad) ^ (r & 7)) * 16));
      uint4v p1 = *(const uint4v*)(Abuf + r * 128 + (((2 * quad + 1) ^ (r & 7)) * 16));
      u32 uu[8] = {p0.x, p0.y, p0.z, p0.w, p1.x, p1.y, p1.z, p1.w};
      short8 ah, al;
      #pragma unroll
      for (int e2 = 0; e2 < 8; e2++) {
        ah[e2] = (short)(uu[e2] & 0xffffu);
        al[e2] = (short)(uu[e2] >> 16);
      }
      #pragma unroll
      for (int j = 0; j < 4; j++) {
        acc[mt][j] = __builtin_amdgcn_mfma_f32_16x16x32_bf16(ah, bh[j], acc[mt][j], 0, 0, 0);
        acc[mt][j] = __builtin_amdgcn_mfma_f32_16x16x32_bf16(ah, bl[j], acc[mt][j], 0, 0, 0);
        acc[mt][j] = __builtin_amdgcn_mfma_f32_16x16x32_bf16(al, bh[j], acc[mt][j], 0, 0, 0);
      }
    }
    __syncthreads();
  }

  // ---- epilogue: wave handles c-chunk cc = ccb*2 + (w>>1); tile j = gate ----
  int c = (ccb * 2 + (w >> 1)) * 16 + m;
  if (c >= H) return;
  float u0r = coefs[c],            u0z = coefs[160 + c],
        u0n = coefs[320 + c];
  float u1r = coefs[VC + c],       u1z = coefs[VC + 160 + c],
        u1n = coefs[VC + 320 + c];
  float bsr = coefs[2 * VC + c],   bsz = coefs[2 * VC + 160 + c],
        bsn = coefs[2 * VC + 320 + c], bsh = coefs[2 * VC + 480 + c];
  #pragma unroll
  for (int mt = 0; mt < 4; mt++) {
    #pragma unroll
    for (int i = 0; i < 4; i++) {
      int row = r0 + mrow0 + mt * 16 + quad * 4 + i;
      if (row >= NN) continue;
      float d0 = (float)(rowptr[2 * row + 1] - rowptr[2 * row]);
      float d1 = (float)(rowptr[2 * row + 2] - rowptr[2 * row + 1]);
      float pr = acc[mt][0][i] + d0 * u0r + d1 * u1r + bsr;
      float pz = acc[mt][1][i] + d0 * u0z + d1 * u1z + bsz;
      float pn = acc[mt][2][i] + d0 * u0n + d1 * u1n + bsn;
      float ph = acc[mt][3][i] + bsh;
      float r_g = 1.f / (1.f + __expf(-pr));
      float z_g = 1.f / (1.f + __expf(-pz));
      float narg = pn + r_g * ph;
      float e2 = __expf(2.f * narg);
      float n_g = 1.f - 2.f / (e2 + 1.f);       // tanh, inf-safe
      float h = upk(npkc[(size_t)row * 160 + c]);
      npkn[(size_t)row * 160 + c] = packf((1.f - z_g) * n_g + z_g * h);
    }
  }
}

// ---------------- readout ----------------
__global__ __launch_bounds__(192) void segsum_kernel(const u32* __restrict__ npk,
                                                     const int* __restrict__ gstart,
                                                     float* __restrict__ gsum) {
  int g = blockIdx.x, chunk = blockIdx.y;
  int c = threadIdx.x;
  if (c >= H) return;
  int s = gstart[g], e = gstart[g + 1];
  int len = e - s;
  if (len <= 0) return;
  int per = (len + 3) / 4;
  int rs = s + chunk * per;
  int re = min(e, rs + per);
  if (rs >= re) return;
  float acc = 0.f;
  for (int r = rs; r < re; r++) acc += upk(npk[(size_t)r * 160 + c]);
  atomicAdd(&gsum[g * H + c], acc);
}

__global__ __launch_bounds__(256) void head_kernel(
    const float* __restrict__ gsum, const float* __restrict__ pt,
    const float* __restrict__ fc1_w, const float* __restrict__ fc1_b,
    const float* __restrict__ fc2_w, const float* __restrict__ fc2_b,
    const float* __restrict__ fcL_w, const float* __restrict__ fcL_b,
    float* __restrict__ out) {
  __shared__ float bufA[NG * 151];
  __shared__ float X1[NG * 80];
  int tid = threadIdx.x;
  for (int e = tid; e < NG * 151; e += 256) {
    int row = e / 151, c = e % 151;
    float v;
    if (c < H) { float g = gsum[row * H + c]; v = (g > 1.f) ? logf(g) : 0.f; }
    else v = pt[row];
    bufA[e] = v;
  }
  __syncthreads();
  for (int e = tid; e < NG * 80; e += 256) {
    int row = e / 80, o = e % 80;
    float acc = fc1_b[o];
    for (int k = 0; k < 151; k++) acc += bufA[row * 151 + k] * fc1_w[o * 151 + k];
    X1[e] = (acc > 0.f) ? acc : 0.01f * acc;
  }
  __syncthreads();
  for (int e = tid; e < NG * 80; e += 256) {
    int row = e / 80, o = e % 80;
    float acc = fc2_b[o];
    for (int k = 0; k < 80; k++) acc += X1[row * 80 + k] * fc2_w[o * 80 + k];
    bufA[e] = (acc > 0.f) ? acc : 0.01f * acc;
  }
  __syncthreads();
  for (int e = tid; e < NG * 10; e += 256) {
    int row = e / 10, o = e % 10;
    float acc = fcL_b[o];
    for (int k = 0; k < 80; k++) acc += bufA[row * 80 + k] * fcL_w[o * 80 + k];
    out[e] = acc;
  }
}

extern "C" void kernel_launch(void* const* d_in, const int* in_sizes, int n_in,
                              void* d_out, int out_size, void* d_ws, size_t ws_size,
                              hipStream_t stream) {
  const float* nodes_in = (const float*)d_in[0];
  const float* problem_type = (const float*)d_in[1];
  const float* edge_W = (const float*)d_in[2];
  const float* edge_b = (const float*)d_in[3];
  const float* w_ih = (const float*)d_in[4];
  const float* w_hh = (const float*)d_in[5];
  const float* b_ih = (const float*)d_in[6];
  const float* b_hh = (const float*)d_in[7];
  const float* fc1_w = (const float*)d_in[8];
  const float* fc1_b = (const float*)d_in[9];
  const float* fc2_w = (const float*)d_in[10];
  const float* fc2_b = (const float*)d_in[11];
  const float* fcL_w = (const float*)d_in[12];
  const float* fcL_b = (const float*)d_in[13];
  const int* edges = (const int*)d_in[14];
  const int* graph_ids = (const int*)d_in[15];

  char* ws = (char*)d_ws;
  size_t off = 0;
  auto alloc = [&](size_t bytes) -> void* {
    void* p = ws + off;
    off = (off + bytes + 255) & ~(size_t)255;
    return p;
  };
  u32* npkA     = (u32*)alloc((size_t)NN * 160 * 4);           // 32 MB
  u32* npkB     = (u32*)alloc((size_t)NN * 160 * 4);           // 32 MB
  u16* Sh       = (u16*)alloc((size_t)NN * 320 * 2);           // 32 MB
  u16* Sl       = (u16*)alloc((size_t)NN * 320 * 2);           // 32 MB
  u16* Bh       = (u16*)alloc((size_t)VC * KB * 2);            // 0.61 MB
  u16* Bl       = (u16*)alloc((size_t)VC * KB * 2);            // 0.61 MB
  float* coefs  = (float*)alloc(3 * VC * 4);
  int* rowptr   = (int*)alloc((2 * NN + 1) * 4);
  int* cursor   = (int*)alloc(2 * NN * 4);
  u16* colbuf   = (u16*)alloc(2ull * NE * 2);                  // 1.6 MB
  int* bsum     = (int*)alloc(128 * 4);
  int* boff     = (int*)alloc(128 * 4);
  int* gstart   = (int*)alloc((NG + 1) * 4);
  float* gsum   = (float*)alloc((size_t)NG * H * 4);

  const int n2 = 2 * NN;                 // 100000 counters
  const int nb = (n2 + 1023) / 1024;     // 98 scan blocks

  // ---- one-time setup ----
  hipMemsetAsync(cursor, 0, n2 * 4, stream);
  hist_kernel<<<(2 * NE + 255) / 256, 256, 0, stream>>>(edges, cursor);
  scan1_kernel<<<nb, 1024, 0, stream>>>(cursor, rowptr, bsum, n2);
  scan2_kernel<<<1, 128, 0, stream>>>(bsum, boff, nb);
  scan3_kernel<<<(n2 + 255) / 256, 256, 0, stream>>>(rowptr, boff, n2);
  total_kernel<<<1, 64, 0, stream>>>(rowptr, boff, n2, nb);
  copy_int_kernel<<<(n2 + 255) / 256, 256, 0, stream>>>(rowptr, cursor, n2);
  fill_kernel<<<(2 * NE + 255) / 256, 256, 0, stream>>>(edges, cursor, colbuf);
  bounds_kernel<<<1, 128, 0, stream>>>(graph_ids, gstart);
  build_B_kernel<<<(VC * KB + 255) / 256, 256, 0, stream>>>(w_ih, w_hh, edge_W, Bh, Bl);
  build_coef_kernel<<<(VC + 255) / 256, 256, 0, stream>>>(w_ih, edge_b, b_ih, b_hh, coefs);
  init_nodes_kernel<<<(NN * 160 + 255) / 256, 256, 0, stream>>>(nodes_in, npkA, npkB);
  pad_S_kernel<<<(NN * 20 + 255) / 256, 256, 0, stream>>>(Sh, Sl);

  // ---- 5 message-passing iterations (packed nodes ping-pong) ----
  const int ngrp = (NRB + 7) / 8;        // 49 groups of 8 row-blocks
  u32* nbuf[2] = {npkA, npkB};
  for (int pass = 0; pass < NPASS; pass++) {
    u32* cur = nbuf[pass & 1];
    u32* nxt = nbuf[1 - (pass & 1)];
    gather_kernel<<<(NN * 64 + 255) / 256, 256, 0, stream>>>(cur, rowptr, colbuf, Sh, Sl);
    gru_gemm_kernel<<<ngrp * 5 * 8, 256, 0, stream>>>(
        Sh, Sl, cur, Bh, Bl, coefs, rowptr, nxt);
  }
  u32* fin = nbuf[NPASS & 1];

  // ---- readout ----
  hipMemsetAsync(gsum, 0, (size_t)NG * H * 4, stream);
  segsum_kernel<<<dim3(NG, 4), 192, 0, stream>>>(fin, gstart, gsum);
  head_kernel<<<1, 256, 0, stream>>>(gsum, problem_type, fc1_w, fc1_b, fc2_w, fc2_b,
                                     fcL_w, fcL_b, (float*)d_out);
}

// Round 10
// 1283.680 us; speedup vs baseline: 2.1470x; 1.0793x over previous
//
#include <hip/hip_runtime.h>
#include <stdint.h>

#define NN 50000
#define H 150
#define NE 400000
#define NG 64
#define NPASS 5
#define KB 480          // GRU GEMM K: [S0(160) | S1(160) | nodes(160)]
#define VC 640          // 40 col-tiles: v = cc*64 + g*16 + cl, c = cc*16+cl
#define NRB 391         // row blocks of 128

typedef unsigned short u16;
typedef unsigned int u32;
typedef __attribute__((ext_vector_type(8))) short short8;
typedef __attribute__((ext_vector_type(4))) float float4v;
typedef __attribute__((ext_vector_type(4))) u32 uint4v;

// ---------------- helpers ----------------
__device__ __forceinline__ u16 f2bf_rn(float x) {
  union { float f; u32 u; } v; v.f = x;
  u32 r = v.u + 0x7fffu + ((v.u >> 16) & 1u);
  return (u16)(r >> 16);
}
__device__ __forceinline__ float bf2f(u16 h) {
  union { u32 u; float f; } v; v.u = ((u32)h) << 16;
  return v.f;
}
// packed node word: low16 = hi bf16, high16 = lo bf16; value = hi + lo
__device__ __forceinline__ u32 packf(float v) {
  u16 hi = f2bf_rn(v);
  u16 lo = f2bf_rn(v - bf2f(hi));
  return (u32)hi | ((u32)lo << 16);
}
__device__ __forceinline__ float upk(u32 u) {
  union { u32 u; float f; } a, b;
  a.u = u << 16; b.u = u & 0xffff0000u;
  return a.f + b.f;
}
// async global->LDS, 16B per lane; lds dest must be wave-uniform base
__device__ __forceinline__ void async16(const void* g, void* l) {
  __builtin_amdgcn_global_load_lds(
      (const __attribute__((address_space(1))) unsigned int*)(uintptr_t)g,
      (__attribute__((address_space(3))) unsigned int*)(uint32_t)(uintptr_t)l,
      16, 0, 0);
}

// ---------------- CSR build (key = node*2 + set) ----------------
__global__ void hist_kernel(const int* __restrict__ edges, int* __restrict__ cnt) {
  int id = blockIdx.x * 256 + threadIdx.x;
  if (id >= 2 * NE) return;
  int dst = edges[id * 2];
  int set = id / NE;
  atomicAdd(&cnt[dst * 2 + set], 1);
}

__global__ __launch_bounds__(1024) void scan1_kernel(const int* __restrict__ cnt,
                                                     int* __restrict__ rowptr,
                                                     int* __restrict__ bsum, int n) {
  __shared__ int sd[1024];
  int t = threadIdx.x;
  int idx = blockIdx.x * 1024 + t;
  int v = (idx < n) ? cnt[idx] : 0;
  sd[t] = v;
  __syncthreads();
  for (int off = 1; off < 1024; off <<= 1) {
    int add = (t >= off) ? sd[t - off] : 0;
    __syncthreads();
    sd[t] += add;
    __syncthreads();
  }
  if (idx < n) rowptr[idx] = sd[t] - v;     // block-local exclusive
  if (t == 1023) bsum[blockIdx.x] = sd[1023];
}

__global__ __launch_bounds__(128) void scan2_kernel(const int* __restrict__ bsum,
                                                    int* __restrict__ boff, int nb) {
  __shared__ int sd[128];
  int t = threadIdx.x;
  int v = (t < nb) ? bsum[t] : 0;
  sd[t] = v;
  __syncthreads();
  for (int off = 1; off < 128; off <<= 1) {
    int add = (t >= off) ? sd[t - off] : 0;
    __syncthreads();
    sd[t] += add;
    __syncthreads();
  }
  boff[t] = sd[t] - v;                       // exclusive; boff[nb] = total
}

__global__ void scan3_kernel(int* __restrict__ rowptr, const int* __restrict__ boff, int n) {
  int idx = blockIdx.x * 256 + threadIdx.x;
  if (idx < n) rowptr[idx] += boff[idx >> 10];
}

__global__ void total_kernel(int* __restrict__ rowptr, const int* __restrict__ boff, int n, int nb) {
  if (threadIdx.x == 0 && blockIdx.x == 0) rowptr[n] = boff[nb];
}

__global__ void copy_int_kernel(const int* __restrict__ a, int* __restrict__ b, int n) {
  int id = blockIdx.x * 256 + threadIdx.x;
  if (id < n) b[id] = a[id];
}

__global__ void fill_kernel(const int* __restrict__ edges, int* __restrict__ cursor,
                            u16* __restrict__ colbuf) {
  int id = blockIdx.x * 256 + threadIdx.x;
  if (id >= 2 * NE) return;
  int dst = edges[id * 2];
  int src = edges[id * 2 + 1];
  int set = id / NE;
  int pos = atomicAdd(&cursor[dst * 2 + set], 1);
  colbuf[pos] = (u16)src;
}

__global__ void bounds_kernel(const int* __restrict__ gids, int* __restrict__ gstart) {
  int g = threadIdx.x;
  if (g > NG) return;
  int lo = 0, hi = NN;
  while (lo < hi) { int m = (lo + hi) >> 1; if (gids[m] < g) lo = m + 1; else hi = m; }
  gstart[g] = lo;
}

// ---------------- one-time weight prep ----------------
// B'[v][k], v in [0,640): g=(v>>4)&3, c=(v>>6)*16+(v&15)
// k<160: (W_ihg @ W0)[c][k]      (g<3; g3=0)
// 160<=k<320: (W_ihg @ W1)[c][k-160]
// 320<=k<480: g0: w_hh[c][kk], g1: w_hh[150+c][kk], g3: w_hh[300+c][kk], g2: 0
__global__ void build_B_kernel(const float* __restrict__ wih, const float* __restrict__ whh,
                               const float* __restrict__ eW,
                               u16* __restrict__ Bh, u16* __restrict__ Bl) {
  int id = blockIdx.x * 256 + threadIdx.x;
  if (id >= VC * KB) return;
  int v = id / KB, k = id % KB;
  int g = (v >> 4) & 3, c = (v >> 6) * 16 + (v & 15);
  int seg = k / 160, kk = k % 160;
  float val = 0.f;
  if (c < H && kk < H) {
    if (seg < 2) {
      if (g < 3) {
        const float* wr = wih + (size_t)(g * H + c) * H;
        const float* wc = eW + (size_t)seg * H * H + kk;
        float acc = 0.f;
        for (int t = 0; t < H; t++) acc += wr[t] * wc[(size_t)t * H];
        val = acc;
      }
    } else {
      if (g == 0) val = whh[(size_t)c * H + kk];
      else if (g == 1) val = whh[(size_t)(H + c) * H + kk];
      else if (g == 3) val = whh[(size_t)(2 * H + c) * H + kk];
    }
  }
  u16 h = f2bf_rn(val);
  Bh[id] = h;
  Bl[id] = f2bf_rn(val - bf2f(h));
}

// coefs[0][g*160+c] = W_ihg @ b0 (deg0 coef), coefs[1] = W_ihg @ b1, coefs[2] = gate bias
__global__ void build_coef_kernel(const float* __restrict__ wih,
                                  const float* __restrict__ eb,
                                  const float* __restrict__ bih, const float* __restrict__ bhh,
                                  float* __restrict__ coefs) {
  int id = threadIdx.x + blockIdx.x * 256;
  if (id >= VC) return;
  int g = id / 160, c = id % 160;
  float u0 = 0.f, u1 = 0.f, bs = 0.f;
  if (c < H) {
    if (g < 3) {
      const float* wr = wih + (size_t)(g * H + c) * H;
      for (int t = 0; t < H; t++) { u0 += wr[t] * eb[t]; u1 += wr[t] * eb[H + t]; }
    }
    if (g == 0) bs = bih[c] + bhh[c];
    else if (g == 1) bs = bih[H + c] + bhh[H + c];
    else if (g == 2) bs = bih[2 * H + c];
    else bs = bhh[2 * H + c];
  }
  coefs[id] = u0;
  coefs[VC + id] = u1;
  coefs[2 * VC + id] = bs;
}

// pack input nodes into npkA; zero pad cols of both buffers
__global__ void init_nodes_kernel(const float* __restrict__ nin,
                                  u32* __restrict__ npkA, u32* __restrict__ npkB) {
  int id = blockIdx.x * 256 + threadIdx.x;
  if (id >= NN * 160) return;
  int r = id / 160, c = id % 160;
  if (c < H) {
    npkA[id] = packf(nin[(size_t)r * H + c]);
  } else {
    npkA[id] = 0;
    npkB[id] = 0;
  }
}

__global__ void pad_S_kernel(u16* __restrict__ Sh, u16* __restrict__ Sl) {
  int id = blockIdx.x * 256 + threadIdx.x;
  if (id >= NN * 20) return;
  int r = id / 20, rem = id % 20;
  int set = rem / 10, t = rem % 10;
  size_t off = (size_t)r * 320 + set * 160 + H + t;
  Sh[off] = 0; Sl[off] = 0;
}

// ---------------- gather: S[n][set*160+c] = sum of raw node rows ----------------
// 2-edge manual unroll: doubles outstanding loads in the latency-bound degree loop.
__global__ __launch_bounds__(256) void gather_kernel(
    const u32* __restrict__ npk, const int* __restrict__ rowptr,
    const u16* __restrict__ colbuf, u16* __restrict__ Sh, u16* __restrict__ Sl) {
  int gtid = blockIdx.x * 256 + threadIdx.x;
  int node = gtid >> 6;
  int lane = gtid & 63;
  if (node >= NN) return;
  int s = rowptr[2 * node], mid = rowptr[2 * node + 1], e = rowptr[2 * node + 2];
  int c0 = lane, c1 = lane + 64, c2 = lane + 128;
  bool ok2 = (c2 < H);
  float a0 = 0.f, a1 = 0.f, a2 = 0.f;
  int p = s;
  for (; p + 1 < mid; p += 2) {
    const u32* rA = npk + (size_t)colbuf[p] * 160;
    const u32* rB = npk + (size_t)colbuf[p + 1] * 160;
    u32 xa0 = rA[c0], xa1 = rA[c1];
    u32 xb0 = rB[c0], xb1 = rB[c1];
    u32 xa2 = 0, xb2 = 0;
    if (ok2) { xa2 = rA[c2]; xb2 = rB[c2]; }
    a0 += upk(xa0) + upk(xb0);
    a1 += upk(xa1) + upk(xb1);
    if (ok2) a2 += upk(xa2) + upk(xb2);
  }
  if (p < mid) {
    const u32* rA = npk + (size_t)colbuf[p] * 160;
    a0 += upk(rA[c0]); a1 += upk(rA[c1]); if (ok2) a2 += upk(rA[c2]);
  }
  float b0 = 0.f, b1 = 0.f, b2 = 0.f;
  p = mid;
  for (; p + 1 < e; p += 2) {
    const u32* rA = npk + (size_t)colbuf[p] * 160;
    const u32* rB = npk + (size_t)colbuf[p + 1] * 160;
    u32 xa0 = rA[c0], xa1 = rA[c1];
    u32 xb0 = rB[c0], xb1 = rB[c1];
    u32 xa2 = 0, xb2 = 0;
    if (ok2) { xa2 = rA[c2]; xb2 = rB[c2]; }
    b0 += upk(xa0) + upk(xb0);
    b1 += upk(xa1) + upk(xb1);
    if (ok2) b2 += upk(xa2) + upk(xb2);
  }
  if (p < e) {
    const u32* rA = npk + (size_t)colbuf[p] * 160;
    b0 += upk(rA[c0]); b1 += upk(rA[c1]); if (ok2) b2 += upk(rA[c2]);
  }
  u16* oh = Sh + (size_t)node * 320;
  u16* ol = Sl + (size_t)node * 320;
  u16 h;
  h = f2bf_rn(a0); oh[c0] = h; ol[c0] = f2bf_rn(a0 - bf2f(h));
  h = f2bf_rn(a1); oh[c1] = h; ol[c1] = f2bf_rn(a1 - bf2f(h));
  if (ok2) { h = f2bf_rn(a2); oh[c2] = h; ol[c2] = f2bf_rn(a2 - bf2f(h)); }
  h = f2bf_rn(b0); oh[160 + c0] = h; ol[160 + c0] = f2bf_rn(b0 - bf2f(h));
  h = f2bf_rn(b1); oh[160 + c1] = h; ol[160 + c1] = f2bf_rn(b1 - bf2f(h));
  if (ok2) { h = f2bf_rn(b2); oh[160 + c2] = h; ol[160 + c2] = f2bf_rn(b2 - bf2f(h)); }
}

// ---------------- fused GRU GEMM: C[NN x 640] = X[NN x 480] @ B'^T, epilogue gates ----
// 128x128 tile, 256 thr / 4 waves; wave w: rows [(w&1)*64,+64) (4 mt) x cols
// [(w>>1)*64,+64) (4 gate-tiles of one c-chunk -> in-register gate combine).
// acc = 64 VGPR/wave, NO min-wave launch-bounds cap (R6 spill lesson).
// BK=32 (m132 lesson), 32KB LDS. XCD swizzle (R7-proven: FETCH 278->68 MB).
// Phase 2 A = packed u32 nodes, shift-unpack.
__global__ __launch_bounds__(256) void gru_gemm_kernel(
    const u16* __restrict__ Sh, const u16* __restrict__ Sl,
    const u32* __restrict__ npkc,
    const u16* __restrict__ Bh, const u16* __restrict__ Bl,
    const float* __restrict__ coefs, const int* __restrict__ rowptr,
    u32* __restrict__ npkn) {
  __shared__ char Abuf[16384];   // p1: [0,8K)=hi,[8K,16K)=lo ; p2: packed u32 tile
  __shared__ char Bbuf[16384];   // [0,8K)=hi, [8K,16K)=lo
  const int bid = blockIdx.x;
  const int xcd = bid & 7;
  const int rest = bid >> 3;
  const int ccb = rest % 5;
  const int r0b = (rest / 5) * 8 + xcd;
  if (r0b >= NRB) return;
  const int r0 = r0b * 128;
  const int tid = threadIdx.x;
  const int w = tid >> 6, l = tid & 63;
  const int m = l & 15, quad = l >> 4;
  const int mrow0 = (w & 1) * 64;
  const int nco0 = (w >> 1) * 64;

  float4v acc[4][4];
  #pragma unroll
  for (int mt = 0; mt < 4; mt++)
    #pragma unroll
    for (int j = 0; j < 4; j++) acc[mt][j] = (float4v){0.f, 0.f, 0.f, 0.f};

  // ---- K phase 1: S half (bf16 hi/lo), kt 0..9 ----
  #pragma unroll 1
  for (int kt = 0; kt < 10; kt++) {
    int koff = kt * 32;
    #pragma unroll
    for (int i = 0; i < 2; i++) {
      int cl = i * 256 + tid;                     // [0,512)
      int row = cl >> 2;
      int q = (cl & 3) ^ ((row >> 1) & 3);
      int rg = min(r0 + row, NN - 1);
      size_t go = (size_t)rg * 320 + koff + q * 8;
      int lb = i * 4096 + w * 1024;
      async16(Sh + go, Abuf + lb);
      async16(Sl + go, Abuf + 8192 + lb);
      size_t gb = (size_t)(ccb * 128 + row) * KB + koff + q * 8;
      async16(Bh + gb, Bbuf + lb);
      async16(Bl + gb, Bbuf + 8192 + lb);
    }
    __syncthreads();
    short8 bh[4], bl[4];
    #pragma unroll
    for (int j = 0; j < 4; j++) {
      int br = nco0 + j * 16 + m;
      int bd = br * 64 + ((quad ^ ((br >> 1) & 3)) * 16);
      bh[j] = *(const short8*)(Bbuf + bd);
      bl[j] = *(const short8*)(Bbuf + 8192 + bd);
    }
    #pragma unroll
    for (int mt = 0; mt < 4; mt++) {
      int r = mrow0 + mt * 16 + m;
      int ad = r * 64 + ((quad ^ ((r >> 1) & 3)) * 16);
      short8 ah = *(const short8*)(Abuf + ad);
      short8 al = *(const short8*)(Abuf + 8192 + ad);
      #pragma unroll
      for (int j = 0; j < 4; j++) {
        acc[mt][j] = __builtin_amdgcn_mfma_f32_16x16x32_bf16(ah, bh[j], acc[mt][j], 0, 0, 0);
        acc[mt][j] = __builtin_amdgcn_mfma_f32_16x16x32_bf16(ah, bl[j], acc[mt][j], 0, 0, 0);
        acc[mt][j] = __builtin_amdgcn_mfma_f32_16x16x32_bf16(al, bh[j], acc[mt][j], 0, 0, 0);
      }
    }
    __syncthreads();
  }

  // ---- K phase 2: nodes half (packed u32, shift-unpack), kt 10..14 ----
  #pragma unroll 1
  for (int kt = 0; kt < 5; kt++) {
    int koff = kt * 32;
    #pragma unroll
    for (int i = 0; i < 4; i++) {
      int cl = i * 256 + tid;                     // [0,1024)
      int row = cl >> 3;
      int q = (cl & 7) ^ (row & 7);
      int rg = min(r0 + row, NN - 1);
      async16(npkc + (size_t)rg * 160 + koff + q * 4, Abuf + i * 4096 + w * 1024);
    }
    #pragma unroll
    for (int i = 0; i < 2; i++) {
      int cl = i * 256 + tid;
      int row = cl >> 2;
      int q = (cl & 3) ^ ((row >> 1) & 3);
      size_t gb = (size_t)(ccb * 128 + row) * KB + 320 + koff + q * 8;
      int lb = i * 4096 + w * 1024;
      async16(Bh + gb, Bbuf + lb);
      async16(Bl + gb, Bbuf + 8192 + lb);
    }
    __syncthreads();
    short8 bh[4], bl[4];
    #pragma unroll
    for (int j = 0; j < 4; j++) {
      int br = nco0 + j * 16 + m;
      int bd = br * 64 + ((quad ^ ((br >> 1) & 3)) * 16);
      bh[j] = *(const short8*)(Bbuf + bd);
      bl[j] = *(const short8*)(Bbuf + 8192 + bd);
    }
    #pragma unroll
    for (int mt = 0; mt < 4; mt++) {
      int r = mrow0 + mt * 16 + m;
      uint4v p0 = *(const uint4v*)(Abuf + r * 128 + (((2 * quad) ^ (r & 7)) * 16));
      uint4v p1 = *(const uint4v*)(Abuf + r * 128 + (((2 * quad + 1) ^ (r & 7)) * 16));
      u32 uu[8] = {p0.x, p0.y, p0.z, p0.w, p1.x, p1.y, p1.z, p1.w};
      short8 ah, al;
      #pragma unroll
      for (int e2 = 0; e2 < 8; e2++) {
        ah[e2] = (short)(uu[e2] & 0xffffu);
        al[e2] = (short)(uu[e2] >> 16);
      }
      #pragma unroll
      for (int j = 0; j < 4; j++) {
        acc[mt][j] = __builtin_amdgcn_mfma_f32_16x16x32_bf16(ah, bh[j], acc[mt][j], 0, 0, 0);
        acc[mt][j] = __builtin_amdgcn_mfma_f32_16x16x32_bf16(ah, bl[j], acc[mt][j], 0, 0, 0);
        acc[mt][j] = __builtin_amdgcn_mfma_f32_16x16x32_bf16(al, bh[j], acc[mt][j], 0, 0, 0);
      }
    }
    __syncthreads();
  }

  // ---- epilogue: wave handles c-chunk cc = ccb*2 + (w>>1); tile j = gate ----
  int c = (ccb * 2 + (w >> 1)) * 16 + m;
  if (c >= H) return;
  float u0r = coefs[c],            u0z = coefs[160 + c],
        u0n = coefs[320 + c];
  float u1r = coefs[VC + c],       u1z = coefs[VC + 160 + c],
        u1n = coefs[VC + 320 + c];
  float bsr = coefs[2 * VC + c],   bsz = coefs[2 * VC + 160 + c],
        bsn = coefs[2 * VC + 320 + c], bsh = coefs[2 * VC + 480 + c];
  #pragma unroll
  for (int mt = 0; mt < 4; mt++) {
    #pragma unroll
    for (int i = 0; i < 4; i++) {
      int row = r0 + mrow0 + mt * 16 + quad * 4 + i;
      if (row >= NN) continue;
      float d0 = (float)(rowptr[2 * row + 1] - rowptr[2 * row]);
      float d1 = (float)(rowptr[2 * row + 2] - rowptr[2 * row + 1]);
      float pr = acc[mt][0][i] + d0 * u0r + d1 * u1r + bsr;
      float pz = acc[mt][1][i] + d0 * u0z + d1 * u1z + bsz;
      float pn = acc[mt][2][i] + d0 * u0n + d1 * u1n + bsn;
      float ph = acc[mt][3][i] + bsh;
      float r_g = 1.f / (1.f + __expf(-pr));
      float z_g = 1.f / (1.f + __expf(-pz));
      float narg = pn + r_g * ph;
      float e2 = __expf(2.f * narg);
      float n_g = 1.f - 2.f / (e2 + 1.f);       // tanh, inf-safe
      float h = upk(npkc[(size_t)row * 160 + c]);
      npkn[(size_t)row * 160 + c] = packf((1.f - z_g) * n_g + z_g * h);
    }
  }
}

// ---------------- readout ----------------
__global__ __launch_bounds__(192) void segsum_kernel(const u32* __restrict__ npk,
                                                     const int* __restrict__ gstart,
                                                     float* __restrict__ gsum) {
  int g = blockIdx.x, chunk = blockIdx.y;
  int c = threadIdx.x;
  if (c >= H) return;
  int s = gstart[g], e = gstart[g + 1];
  int len = e - s;
  if (len <= 0) return;
  int per = (len + 3) / 4;
  int rs = s + chunk * per;
  int re = min(e, rs + per);
  if (rs >= re) return;
  float acc = 0.f;
  for (int r = rs; r < re; r++) acc += upk(npk[(size_t)r * 160 + c]);
  atomicAdd(&gsum[g * H + c], acc);
}

// one block per graph row; 192 thr. LDS: x[151], x1[80], x2[80].
__global__ __launch_bounds__(192) void head_kernel(
    const float* __restrict__ gsum, const float* __restrict__ pt,
    const float* __restrict__ fc1_w, const float* __restrict__ fc1_b,
    const float* __restrict__ fc2_w, const float* __restrict__ fc2_b,
    const float* __restrict__ fcL_w, const float* __restrict__ fcL_b,
    float* __restrict__ out) {
  __shared__ float x[151];
  __shared__ float x1[80];
  __shared__ float x2[80];
  int row = blockIdx.x;
  int t = threadIdx.x;
  if (t < 151) {
    float v;
    if (t < H) { float g = gsum[row * H + t]; v = (g > 1.f) ? logf(g) : 0.f; }
    else v = pt[row];
    x[t] = v;
  }
  __syncthreads();
  if (t < 80) {
    float acc = fc1_b[t];
    const float* wrow = fc1_w + t * 151;
    #pragma unroll 4
    for (int k = 0; k < 151; k++) acc += x[k] * wrow[k];
    x1[t] = (acc > 0.f) ? acc : 0.01f * acc;
  }
  __syncthreads();
  if (t < 80) {
    float acc = fc2_b[t];
    const float* wrow = fc2_w + t * 80;
    #pragma unroll 4
    for (int k = 0; k < 80; k++) acc += x1[k] * wrow[k];
    x2[t] = (acc > 0.f) ? acc : 0.01f * acc;
  }
  __syncthreads();
  if (t < 10) {
    float acc = fcL_b[t];
    const float* wrow = fcL_w + t * 80;
    #pragma unroll 4
    for (int k = 0; k < 80; k++) acc += x2[k] * wrow[k];
    out[row * 10 + t] = acc;
  }
}

extern "C" void kernel_launch(void* const* d_in, const int* in_sizes, int n_in,
                              void* d_out, int out_size, void* d_ws, size_t ws_size,
                              hipStream_t stream) {
  const float* nodes_in = (const float*)d_in[0];
  const float* problem_type = (const float*)d_in[1];
  const float* edge_W = (const float*)d_in[2];
  const float* edge_b = (const float*)d_in[3];
  const float* w_ih = (const float*)d_in[4];
  const float* w_hh = (const float*)d_in[5];
  const float* b_ih = (const float*)d_in[6];
  const float* b_hh = (const float*)d_in[7];
  const float* fc1_w = (const float*)d_in[8];
  const float* fc1_b = (const float*)d_in[9];
  const float* fc2_w = (const float*)d_in[10];
  const float* fc2_b = (const float*)d_in[11];
  const float* fcL_w = (const float*)d_in[12];
  const float* fcL_b = (const float*)d_in[13];
  const int* edges = (const int*)d_in[14];
  const int* graph_ids = (const int*)d_in[15];

  char* ws = (char*)d_ws;
  size_t off = 0;
  auto alloc = [&](size_t bytes) -> void* {
    void* p = ws + off;
    off = (off + bytes + 255) & ~(size_t)255;
    return p;
  };
  u32* npkA     = (u32*)alloc((size_t)NN * 160 * 4);           // 32 MB
  u32* npkB     = (u32*)alloc((size_t)NN * 160 * 4);           // 32 MB
  u16* Sh       = (u16*)alloc((size_t)NN * 320 * 2);           // 32 MB
  u16* Sl       = (u16*)alloc((size_t)NN * 320 * 2);           // 32 MB
  u16* Bh       = (u16*)alloc((size_t)VC * KB * 2);            // 0.61 MB
  u16* Bl       = (u16*)alloc((size_t)VC * KB * 2);            // 0.61 MB
  float* coefs  = (float*)alloc(3 * VC * 4);
  int* rowptr   = (int*)alloc((2 * NN + 1) * 4);
  int* cursor   = (int*)alloc(2 * NN * 4);
  u16* colbuf   = (u16*)alloc(2ull * NE * 2);                  // 1.6 MB
  int* bsum     = (int*)alloc(128 * 4);
  int* boff     = (int*)alloc(128 * 4);
  int* gstart   = (int*)alloc((NG + 1) * 4);
  float* gsum   = (float*)alloc((size_t)NG * H * 4);

  const int n2 = 2 * NN;                 // 100000 counters
  const int nb = (n2 + 1023) / 1024;     // 98 scan blocks

  // ---- one-time setup ----
  hipMemsetAsync(cursor, 0, n2 * 4, stream);
  hist_kernel<<<(2 * NE + 255) / 256, 256, 0, stream>>>(edges, cursor);
  scan1_kernel<<<nb, 1024, 0, stream>>>(cursor, rowptr, bsum, n2);
  scan2_kernel<<<1, 128, 0, stream>>>(bsum, boff, nb);
  scan3_kernel<<<(n2 + 255) / 256, 256, 0, stream>>>(rowptr, boff, n2);
  total_kernel<<<1, 64, 0, stream>>>(rowptr, boff, n2, nb);
  copy_int_kernel<<<(n2 + 255) / 256, 256, 0, stream>>>(rowptr, cursor, n2);
  fill_kernel<<<(2 * NE + 255) / 256, 256, 0, stream>>>(edges, cursor, colbuf);
  bounds_kernel<<<1, 128, 0, stream>>>(graph_ids, gstart);
  build_B_kernel<<<(VC * KB + 255) / 256, 256, 0, stream>>>(w_ih, w_hh, edge_W, Bh, Bl);
  build_coef_kernel<<<(VC + 255) / 256, 256, 0, stream>>>(w_ih, edge_b, b_ih, b_hh, coefs);
  init_nodes_kernel<<<(NN * 160 + 255) / 256, 256, 0, stream>>>(nodes_in, npkA, npkB);
  pad_S_kernel<<<(NN * 20 + 255) / 256, 256, 0, stream>>>(Sh, Sl);

  // ---- 5 message-passing iterations (packed nodes ping-pong) ----
  const int ngrp = (NRB + 7) / 8;        // 49 groups of 8 row-blocks
  u32* nbuf[2] = {npkA, npkB};
  for (int pass = 0; pass < NPASS; pass++) {
    u32* cur = nbuf[pass & 1];
    u32* nxt = nbuf[1 - (pass & 1)];
    gather_kernel<<<(NN * 64 + 255) / 256, 256, 0, stream>>>(cur, rowptr, colbuf, Sh, Sl);
    gru_gemm_kernel<<<ngrp * 5 * 8, 256, 0, stream>>>(
        Sh, Sl, cur, Bh, Bl, coefs, rowptr, nxt);
  }
  u32* fin = nbuf[NPASS & 1];

  // ---- readout ----
  hipMemsetAsync(gsum, 0, (size_t)NG * H * 4, stream);
  segsum_kernel<<<dim3(NG, 4), 192, 0, stream>>>(fin, gstart, gsum);
  head_kernel<<<NG, 192, 0, stream>>>(gsum, problem_type, fc1_w, fc1_b, fc2_w, fc2_b,
                                      fcL_w, fcL_b, (float*)d_out);
}

// Round 11
// 1173.430 us; speedup vs baseline: 2.3488x; 1.0940x over previous
//
#include <hip/hip_runtime.h>
#include <stdint.h>

#define NN 50000
#define H 150
#define NE 400000
#define NG 64
#define NPASS 5
#define KB 480          // GRU GEMM K: [S0(160) | S1(160) | nodes(160)]
#define VC 640          // 40 col-tiles: v = cc*64 + g*16 + cl, c = cc*16+cl
#define NRB 391         // row blocks of 128

typedef unsigned short u16;
typedef unsigned int u32;
typedef __attribute__((ext_vector_type(8))) short short8;
typedef __attribute__((ext_vector_type(4))) float float4v;
typedef __attribute__((ext_vector_type(4))) u32 uint4v;

// ---------------- helpers ----------------
__device__ __forceinline__ u16 f2bf_rn(float x) {
  union { float f; u32 u; } v; v.f = x;
  u32 r = v.u + 0x7fffu + ((v.u >> 16) & 1u);
  return (u16)(r >> 16);
}
__device__ __forceinline__ float bf2f(u16 h) {
  union { u32 u; float f; } v; v.u = ((u32)h) << 16;
  return v.f;
}
// packed node word: low16 = hi bf16, high16 = lo bf16; value = hi + lo
__device__ __forceinline__ u32 packf(float v) {
  u16 hi = f2bf_rn(v);
  u16 lo = f2bf_rn(v - bf2f(hi));
  return (u32)hi | ((u32)lo << 16);
}
__device__ __forceinline__ float upk(u32 u) {
  union { u32 u; float f; } a, b;
  a.u = u << 16; b.u = u & 0xffff0000u;
  return a.f + b.f;
}
// async global->LDS, 16B per lane; lds dest must be wave-uniform base
__device__ __forceinline__ void async16(const void* g, void* l) {
  __builtin_amdgcn_global_load_lds(
      (const __attribute__((address_space(1))) unsigned int*)(uintptr_t)g,
      (__attribute__((address_space(3))) unsigned int*)(uint32_t)(uintptr_t)l,
      16, 0, 0);
}

// ---------------- CSR build (key = node*2 + set) ----------------
__global__ void hist_kernel(const int* __restrict__ edges, int* __restrict__ cnt) {
  int id = blockIdx.x * 256 + threadIdx.x;
  if (id >= 2 * NE) return;
  int dst = edges[id * 2];
  int set = id / NE;
  atomicAdd(&cnt[dst * 2 + set], 1);
}

__global__ __launch_bounds__(1024) void scan1_kernel(const int* __restrict__ cnt,
                                                     int* __restrict__ rowptr,
                                                     int* __restrict__ bsum, int n) {
  __shared__ int sd[1024];
  int t = threadIdx.x;
  int idx = blockIdx.x * 1024 + t;
  int v = (idx < n) ? cnt[idx] : 0;
  sd[t] = v;
  __syncthreads();
  for (int off = 1; off < 1024; off <<= 1) {
    int add = (t >= off) ? sd[t - off] : 0;
    __syncthreads();
    sd[t] += add;
    __syncthreads();
  }
  if (idx < n) rowptr[idx] = sd[t] - v;     // block-local exclusive
  if (t == 1023) bsum[blockIdx.x] = sd[1023];
}

__global__ __launch_bounds__(128) void scan2_kernel(const int* __restrict__ bsum,
                                                    int* __restrict__ boff, int nb) {
  __shared__ int sd[128];
  int t = threadIdx.x;
  int v = (t < nb) ? bsum[t] : 0;
  sd[t] = v;
  __syncthreads();
  for (int off = 1; off < 128; off <<= 1) {
    int add = (t >= off) ? sd[t - off] : 0;
    __syncthreads();
    sd[t] += add;
    __syncthreads();
  }
  boff[t] = sd[t] - v;                       // exclusive; boff[nb] = total
}

__global__ void scan3_kernel(int* __restrict__ rowptr, const int* __restrict__ boff, int n) {
  int idx = blockIdx.x * 256 + threadIdx.x;
  if (idx < n) rowptr[idx] += boff[idx >> 10];
}

__global__ void total_kernel(int* __restrict__ rowptr, const int* __restrict__ boff, int n, int nb) {
  if (threadIdx.x == 0 && blockIdx.x == 0) rowptr[n] = boff[nb];
}

__global__ void copy_int_kernel(const int* __restrict__ a, int* __restrict__ b, int n) {
  int id = blockIdx.x * 256 + threadIdx.x;
  if (id < n) b[id] = a[id];
}

__global__ void fill_kernel(const int* __restrict__ edges, int* __restrict__ cursor,
                            u16* __restrict__ colbuf) {
  int id = blockIdx.x * 256 + threadIdx.x;
  if (id >= 2 * NE) return;
  int dst = edges[id * 2];
  int src = edges[id * 2 + 1];
  int set = id / NE;
  int pos = atomicAdd(&cursor[dst * 2 + set], 1);
  colbuf[pos] = (u16)src;
}

__global__ void bounds_kernel(const int* __restrict__ gids, int* __restrict__ gstart) {
  int g = threadIdx.x;
  if (g > NG) return;
  int lo = 0, hi = NN;
  while (lo < hi) { int m = (lo + hi) >> 1; if (gids[m] < g) lo = m + 1; else hi = m; }
  gstart[g] = lo;
}

// ---------------- one-time weight prep ----------------
// B'[v][k], v in [0,640): g=(v>>4)&3, c=(v>>6)*16+(v&15)
// k<160: (W_ihg @ W0)[c][k]      (g<3; g3=0)
// 160<=k<320: (W_ihg @ W1)[c][k-160]
// 320<=k<480: g0: w_hh[c][kk], g1: w_hh[150+c][kk], g3: w_hh[300+c][kk], g2: 0
__global__ void build_B_kernel(const float* __restrict__ wih, const float* __restrict__ whh,
                               const float* __restrict__ eW,
                               u16* __restrict__ Bh, u16* __restrict__ Bl) {
  int id = blockIdx.x * 256 + threadIdx.x;
  if (id >= VC * KB) return;
  int v = id / KB, k = id % KB;
  int g = (v >> 4) & 3, c = (v >> 6) * 16 + (v & 15);
  int seg = k / 160, kk = k % 160;
  float val = 0.f;
  if (c < H && kk < H) {
    if (seg < 2) {
      if (g < 3) {
        const float* wr = wih + (size_t)(g * H + c) * H;
        const float* wc = eW + (size_t)seg * H * H + kk;
        float acc = 0.f;
        for (int t = 0; t < H; t++) acc += wr[t] * wc[(size_t)t * H];
        val = acc;
      }
    } else {
      if (g == 0) val = whh[(size_t)c * H + kk];
      else if (g == 1) val = whh[(size_t)(H + c) * H + kk];
      else if (g == 3) val = whh[(size_t)(2 * H + c) * H + kk];
    }
  }
  u16 h = f2bf_rn(val);
  Bh[id] = h;
  Bl[id] = f2bf_rn(val - bf2f(h));
}

// coefs[0][g*160+c] = W_ihg @ b0 (deg0 coef), coefs[1] = W_ihg @ b1, coefs[2] = gate bias
__global__ void build_coef_kernel(const float* __restrict__ wih,
                                  const float* __restrict__ eb,
                                  const float* __restrict__ bih, const float* __restrict__ bhh,
                                  float* __restrict__ coefs) {
  int id = threadIdx.x + blockIdx.x * 256;
  if (id >= VC) return;
  int g = id / 160, c = id % 160;
  float u0 = 0.f, u1 = 0.f, bs = 0.f;
  if (c < H) {
    if (g < 3) {
      const float* wr = wih + (size_t)(g * H + c) * H;
      for (int t = 0; t < H; t++) { u0 += wr[t] * eb[t]; u1 += wr[t] * eb[H + t]; }
    }
    if (g == 0) bs = bih[c] + bhh[c];
    else if (g == 1) bs = bih[H + c] + bhh[H + c];
    else if (g == 2) bs = bih[2 * H + c];
    else bs = bhh[2 * H + c];
  }
  coefs[id] = u0;
  coefs[VC + id] = u1;
  coefs[2 * VC + id] = bs;
}

// pack input nodes into npkA; zero pad cols of both buffers
__global__ void init_nodes_kernel(const float* __restrict__ nin,
                                  u32* __restrict__ npkA, u32* __restrict__ npkB) {
  int id = blockIdx.x * 256 + threadIdx.x;
  if (id >= NN * 160) return;
  int r = id / 160, c = id % 160;
  if (c < H) {
    npkA[id] = packf(nin[(size_t)r * H + c]);
  } else {
    npkA[id] = 0;
    npkB[id] = 0;
  }
}

__global__ void pad_S_kernel(u16* __restrict__ Sh, u16* __restrict__ Sl) {
  int id = blockIdx.x * 256 + threadIdx.x;
  if (id >= NN * 20) return;
  int r = id / 20, rem = id % 20;
  int set = rem / 10, t = rem % 10;
  size_t off = (size_t)r * 320 + set * 160 + H + t;
  Sh[off] = 0; Sl[off] = 0;
}

// ---------------- gather: S[n][set*160+c] = sum of raw node rows ----------------
// 2-edge manual unroll: doubles outstanding loads in the latency-bound degree loop.
__global__ __launch_bounds__(256) void gather_kernel(
    const u32* __restrict__ npk, const int* __restrict__ rowptr,
    const u16* __restrict__ colbuf, u16* __restrict__ Sh, u16* __restrict__ Sl) {
  int gtid = blockIdx.x * 256 + threadIdx.x;
  int node = gtid >> 6;
  int lane = gtid & 63;
  if (node >= NN) return;
  int s = rowptr[2 * node], mid = rowptr[2 * node + 1], e = rowptr[2 * node + 2];
  int c0 = lane, c1 = lane + 64, c2 = lane + 128;
  bool ok2 = (c2 < H);
  float a0 = 0.f, a1 = 0.f, a2 = 0.f;
  int p = s;
  for (; p + 1 < mid; p += 2) {
    const u32* rA = npk + (size_t)colbuf[p] * 160;
    const u32* rB = npk + (size_t)colbuf[p + 1] * 160;
    u32 xa0 = rA[c0], xa1 = rA[c1];
    u32 xb0 = rB[c0], xb1 = rB[c1];
    u32 xa2 = 0, xb2 = 0;
    if (ok2) { xa2 = rA[c2]; xb2 = rB[c2]; }
    a0 += upk(xa0) + upk(xb0);
    a1 += upk(xa1) + upk(xb1);
    if (ok2) a2 += upk(xa2) + upk(xb2);
  }
  if (p < mid) {
    const u32* rA = npk + (size_t)colbuf[p] * 160;
    a0 += upk(rA[c0]); a1 += upk(rA[c1]); if (ok2) a2 += upk(rA[c2]);
  }
  float b0 = 0.f, b1 = 0.f, b2 = 0.f;
  p = mid;
  for (; p + 1 < e; p += 2) {
    const u32* rA = npk + (size_t)colbuf[p] * 160;
    const u32* rB = npk + (size_t)colbuf[p + 1] * 160;
    u32 xa0 = rA[c0], xa1 = rA[c1];
    u32 xb0 = rB[c0], xb1 = rB[c1];
    u32 xa2 = 0, xb2 = 0;
    if (ok2) { xa2 = rA[c2]; xb2 = rB[c2]; }
    b0 += upk(xa0) + upk(xb0);
    b1 += upk(xa1) + upk(xb1);
    if (ok2) b2 += upk(xa2) + upk(xb2);
  }
  if (p < e) {
    const u32* rA = npk + (size_t)colbuf[p] * 160;
    b0 += upk(rA[c0]); b1 += upk(rA[c1]); if (ok2) b2 += upk(rA[c2]);
  }
  u16* oh = Sh + (size_t)node * 320;
  u16* ol = Sl + (size_t)node * 320;
  u16 h;
  h = f2bf_rn(a0); oh[c0] = h; ol[c0] = f2bf_rn(a0 - bf2f(h));
  h = f2bf_rn(a1); oh[c1] = h; ol[c1] = f2bf_rn(a1 - bf2f(h));
  if (ok2) { h = f2bf_rn(a2); oh[c2] = h; ol[c2] = f2bf_rn(a2 - bf2f(h)); }
  h = f2bf_rn(b0); oh[160 + c0] = h; ol[160 + c0] = f2bf_rn(b0 - bf2f(h));
  h = f2bf_rn(b1); oh[160 + c1] = h; ol[160 + c1] = f2bf_rn(b1 - bf2f(h));
  if (ok2) { h = f2bf_rn(b2); oh[160 + c2] = h; ol[160 + c2] = f2bf_rn(b2 - bf2f(h)); }
}

// ---------------- fused GRU GEMM: C[NN x 640] = X[NN x 480] @ B'^T, epilogue gates ----
// R11: R10 shape (128x128 tile, 256 thr/4 waves, wave = 4mt x one c-chunk's 4 gates,
// XCD swizzle, BK=32) + DOUBLE-BUFFERED LDS with prefetch distance 1:
//   stage(kt+1) issued BEFORE compute(kt); the compiler's forced vmcnt(0) at the
//   single per-kt barrier then drains loads issued a full compute (~900cyc) earlier
//   -> drain ~0. Barriers/block 30 -> 16. LDS 64KB -> 2 blocks/CU (in-block
//   pipelining substitutes for residency).
// Zero-gate skip (exact): B' is 0 for gate3@k<320 and gate2@k>=320 -> skip those
// B stages (wave-uniform predicate), LDS reads, and MFMAs. Bit-identical output.
__global__ __launch_bounds__(256) void gru_gemm_kernel(
    const u16* __restrict__ Sh, const u16* __restrict__ Sl,
    const u32* __restrict__ npkc,
    const u16* __restrict__ Bh, const u16* __restrict__ Bl,
    const float* __restrict__ coefs, const int* __restrict__ rowptr,
    u32* __restrict__ npkn) {
  __shared__ char Abuf[2][16384];  // p1: [0,8K)=hi,[8K,16K)=lo ; p2: packed u32 tile
  __shared__ char Bbuf[2][16384];  // [0,8K)=hi, [8K,16K)=lo
  const int bid = blockIdx.x;
  const int xcd = bid & 7;
  const int rest = bid >> 3;
  const int ccb = rest % 5;
  const int r0b = (rest / 5) * 8 + xcd;
  if (r0b >= NRB) return;
  const int r0 = r0b * 128;
  const int tid = threadIdx.x;
  const int w = tid >> 6, l = tid & 63;
  const int m = l & 15, quad = l >> 4;
  const int mrow0 = (w & 1) * 64;
  const int nco0 = (w >> 1) * 64;

  float4v acc[4][4];
  #pragma unroll
  for (int mt = 0; mt < 4; mt++)
    #pragma unroll
    for (int j = 0; j < 4; j++) acc[mt][j] = (float4v){0.f, 0.f, 0.f, 0.f};

  auto stage = [&](int kt, char* Ab, char* Bb) {
    if (kt < 10) {
      int koff = kt * 32;
      #pragma unroll
      for (int i = 0; i < 2; i++) {
        int cl = i * 256 + tid;                   // [0,512)
        int row = cl >> 2;
        int q = (cl & 3) ^ ((row >> 1) & 3);
        int rg = min(r0 + row, NN - 1);
        size_t go = (size_t)rg * 320 + koff + q * 8;
        int lb = i * 4096 + w * 1024;
        async16(Sh + go, Ab + lb);
        async16(Sl + go, Ab + 8192 + lb);
        if (((row >> 4) & 3) != 3) {              // gate3 rows zero for k<320
          size_t gb = (size_t)(ccb * 128 + row) * KB + koff + q * 8;
          async16(Bh + gb, Bb + lb);
          async16(Bl + gb, Bb + 8192 + lb);
        }
      }
    } else {
      int koff = (kt - 10) * 32;
      #pragma unroll
      for (int i = 0; i < 4; i++) {
        int cl = i * 256 + tid;                   // [0,1024)
        int row = cl >> 3;
        int q = (cl & 7) ^ (row & 7);
        int rg = min(r0 + row, NN - 1);
        async16(npkc + (size_t)rg * 160 + koff + q * 4, Ab + i * 4096 + w * 1024);
      }
      #pragma unroll
      for (int i = 0; i < 2; i++) {
        int cl = i * 256 + tid;
        int row = cl >> 2;
        int q = (cl & 3) ^ ((row >> 1) & 3);
        if (((row >> 4) & 3) != 2) {              // gate2 rows zero for k>=320
          size_t gb = (size_t)(ccb * 128 + row) * KB + 320 + koff + q * 8;
          int lb = i * 4096 + w * 1024;
          async16(Bh + gb, Bb + lb);
          async16(Bl + gb, Bb + 8192 + lb);
        }
      }
    }
  };

  auto compute = [&](int kt, const char* Ab, const char* Bb) {
    if (kt < 10) {
      short8 bh[3], bl[3];
      #pragma unroll
      for (int j = 0; j < 3; j++) {
        int br = nco0 + j * 16 + m;
        int bd = br * 64 + ((quad ^ ((br >> 1) & 3)) * 16);
        bh[j] = *(const short8*)(Bb + bd);
        bl[j] = *(const short8*)(Bb + 8192 + bd);
      }
      #pragma unroll
      for (int mt = 0; mt < 4; mt++) {
        int r = mrow0 + mt * 16 + m;
        int ad = r * 64 + ((quad ^ ((r >> 1) & 3)) * 16);
        short8 ah = *(const short8*)(Ab + ad);
        short8 al = *(const short8*)(Ab + 8192 + ad);
        #pragma unroll
        for (int j = 0; j < 3; j++) {
          acc[mt][j] = __builtin_amdgcn_mfma_f32_16x16x32_bf16(ah, bh[j], acc[mt][j], 0, 0, 0);
          acc[mt][j] = __builtin_amdgcn_mfma_f32_16x16x32_bf16(ah, bl[j], acc[mt][j], 0, 0, 0);
          acc[mt][j] = __builtin_amdgcn_mfma_f32_16x16x32_bf16(al, bh[j], acc[mt][j], 0, 0, 0);
        }
      }
    } else {
      const int jmap[3] = {0, 1, 3};
      short8 bh[3], bl[3];
      #pragma unroll
      for (int jj = 0; jj < 3; jj++) {
        int br = nco0 + jmap[jj] * 16 + m;
        int bd = br * 64 + ((quad ^ ((br >> 1) & 3)) * 16);
        bh[jj] = *(const short8*)(Bb + bd);
        bl[jj] = *(const short8*)(Bb + 8192 + bd);
      }
      #pragma unroll
      for (int mt = 0; mt < 4; mt++) {
        int r = mrow0 + mt * 16 + m;
        uint4v p0 = *(const uint4v*)(Ab + r * 128 + (((2 * quad) ^ (r & 7)) * 16));
        uint4v p1 = *(const uint4v*)(Ab + r * 128 + (((2 * quad + 1) ^ (r & 7)) * 16));
        u32 uu[8] = {p0.x, p0.y, p0.z, p0.w, p1.x, p1.y, p1.z, p1.w};
        short8 ah, al;
        #pragma unroll
        for (int e2 = 0; e2 < 8; e2++) {
          ah[e2] = (short)(uu[e2] & 0xffffu);
          al[e2] = (short)(uu[e2] >> 16);
        }
        #pragma unroll
        for (int jj = 0; jj < 3; jj++) {
          int j = jmap[jj];
          acc[mt][j] = __builtin_amdgcn_mfma_f32_16x16x32_bf16(ah, bh[jj], acc[mt][j], 0, 0, 0);
          acc[mt][j] = __builtin_amdgcn_mfma_f32_16x16x32_bf16(ah, bl[jj], acc[mt][j], 0, 0, 0);
          acc[mt][j] = __builtin_amdgcn_mfma_f32_16x16x32_bf16(al, bh[jj], acc[mt][j], 0, 0, 0);
        }
      }
    }
  };

  // ---- software-pipelined K loop: stage(kt+1) BEFORE compute(kt), 1 barrier/kt ----
  stage(0, Abuf[0], Bbuf[0]);
  __syncthreads();                               // drains stage(0)
  #pragma unroll 1
  for (int kt = 0; kt < 15; kt++) {
    int cur = kt & 1;
    if (kt + 1 < 15) stage(kt + 1, Abuf[cur ^ 1], Bbuf[cur ^ 1]);
    compute(kt, Abuf[cur], Bbuf[cur]);
    __syncthreads();                             // drains kt+1 loads (in flight ~1 compute)
  }

  // ---- epilogue: wave handles c-chunk cc = ccb*2 + (w>>1); tile j = gate ----
  int c = (ccb * 2 + (w >> 1)) * 16 + m;
  if (c >= H) return;
  float u0r = coefs[c],            u0z = coefs[160 + c],
        u0n = coefs[320 + c];
  float u1r = coefs[VC + c],       u1z = coefs[VC + 160 + c],
        u1n = coefs[VC + 320 + c];
  float bsr = coefs[2 * VC + c],   bsz = coefs[2 * VC + 160 + c],
        bsn = coefs[2 * VC + 320 + c], bsh = coefs[2 * VC + 480 + c];
  #pragma unroll
  for (int mt = 0; mt < 4; mt++) {
    #pragma unroll
    for (int i = 0; i < 4; i++) {
      int row = r0 + mrow0 + mt * 16 + quad * 4 + i;
      if (row >= NN) continue;
      float d0 = (float)(rowptr[2 * row + 1] - rowptr[2 * row]);
      float d1 = (float)(rowptr[2 * row + 2] - rowptr[2 * row + 1]);
      float pr = acc[mt][0][i] + d0 * u0r + d1 * u1r + bsr;
      float pz = acc[mt][1][i] + d0 * u0z + d1 * u1z + bsz;
      float pn = acc[mt][2][i] + d0 * u0n + d1 * u1n + bsn;
      float ph = acc[mt][3][i] + bsh;
      float r_g = 1.f / (1.f + __expf(-pr));
      float z_g = 1.f / (1.f + __expf(-pz));
      float narg = pn + r_g * ph;
      float e2 = __expf(2.f * narg);
      float n_g = 1.f - 2.f / (e2 + 1.f);       // tanh, inf-safe
      float h = upk(npkc[(size_t)row * 160 + c]);
      npkn[(size_t)row * 160 + c] = packf((1.f - z_g) * n_g + z_g * h);
    }
  }
}

// ---------------- readout ----------------
__global__ __launch_bounds__(192) void segsum_kernel(const u32* __restrict__ npk,
                                                     const int* __restrict__ gstart,
                                                     float* __restrict__ gsum) {
  int g = blockIdx.x, chunk = blockIdx.y;
  int c = threadIdx.x;
  if (c >= H) return;
  int s = gstart[g], e = gstart[g + 1];
  int len = e - s;
  if (len <= 0) return;
  int per = (len + 3) / 4;
  int rs = s + chunk * per;
  int re = min(e, rs + per);
  if (rs >= re) return;
  float acc = 0.f;
  for (int r = rs; r < re; r++) acc += upk(npk[(size_t)r * 160 + c]);
  atomicAdd(&gsum[g * H + c], acc);
}

// one block per graph row; 192 thr. LDS: x[151], x1[80], x2[80].
__global__ __launch_bounds__(192) void head_kernel(
    const float* __restrict__ gsum, const float* __restrict__ pt,
    const float* __restrict__ fc1_w, const float* __restrict__ fc1_b,
    const float* __restrict__ fc2_w, const float* __restrict__ fc2_b,
    const float* __restrict__ fcL_w, const float* __restrict__ fcL_b,
    float* __restrict__ out) {
  __shared__ float x[151];
  __shared__ float x1[80];
  __shared__ float x2[80];
  int row = blockIdx.x;
  int t = threadIdx.x;
  if (t < 151) {
    float v;
    if (t < H) { float g = gsum[row * H + t]; v = (g > 1.f) ? logf(g) : 0.f; }
    else v = pt[row];
    x[t] = v;
  }
  __syncthreads();
  if (t < 80) {
    float acc = fc1_b[t];
    const float* wrow = fc1_w + t * 151;
    #pragma unroll 4
    for (int k = 0; k < 151; k++) acc += x[k] * wrow[k];
    x1[t] = (acc > 0.f) ? acc : 0.01f * acc;
  }
  __syncthreads();
  if (t < 80) {
    float acc = fc2_b[t];
    const float* wrow = fc2_w + t * 80;
    #pragma unroll 4
    for (int k = 0; k < 80; k++) acc += x1[k] * wrow[k];
    x2[t] = (acc > 0.f) ? acc : 0.01f * acc;
  }
  __syncthreads();
  if (t < 10) {
    float acc = fcL_b[t];
    const float* wrow = fcL_w + t * 80;
    #pragma unroll 4
    for (int k = 0; k < 80; k++) acc += x2[k] * wrow[k];
    out[row * 10 + t] = acc;
  }
}

extern "C" void kernel_launch(void* const* d_in, const int* in_sizes, int n_in,
                              void* d_out, int out_size, void* d_ws, size_t ws_size,
                              hipStream_t stream) {
  const float* nodes_in = (const float*)d_in[0];
  const float* problem_type = (const float*)d_in[1];
  const float* edge_W = (const float*)d_in[2];
  const float* edge_b = (const float*)d_in[3];
  const float* w_ih = (const float*)d_in[4];
  const float* w_hh = (const float*)d_in[5];
  const float* b_ih = (const float*)d_in[6];
  const float* b_hh = (const float*)d_in[7];
  const float* fc1_w = (const float*)d_in[8];
  const float* fc1_b = (const float*)d_in[9];
  const float* fc2_w = (const float*)d_in[10];
  const float* fc2_b = (const float*)d_in[11];
  const float* fcL_w = (const float*)d_in[12];
  const float* fcL_b = (const float*)d_in[13];
  const int* edges = (const int*)d_in[14];
  const int* graph_ids = (const int*)d_in[15];

  char* ws = (char*)d_ws;
  size_t off = 0;
  auto alloc = [&](size_t bytes) -> void* {
    void* p = ws + off;
    off = (off + bytes + 255) & ~(size_t)255;
    return p;
  };
  u32* npkA     = (u32*)alloc((size_t)NN * 160 * 4);           // 32 MB
  u32* npkB     = (u32*)alloc((size_t)NN * 160 * 4);           // 32 MB
  u16* Sh       = (u16*)alloc((size_t)NN * 320 * 2);           // 32 MB
  u16* Sl       = (u16*)alloc((size_t)NN * 320 * 2);           // 32 MB
  u16* Bh       = (u16*)alloc((size_t)VC * KB * 2);            // 0.61 MB
  u16* Bl       = (u16*)alloc((size_t)VC * KB * 2);            // 0.61 MB
  float* coefs  = (float*)alloc(3 * VC * 4);
  int* rowptr   = (int*)alloc((2 * NN + 1) * 4);
  int* cursor   = (int*)alloc(2 * NN * 4);
  u16* colbuf   = (u16*)alloc(2ull * NE * 2);                  // 1.6 MB
  int* bsum     = (int*)alloc(128 * 4);
  int* boff     = (int*)alloc(128 * 4);
  int* gstart   = (int*)alloc((NG + 1) * 4);
  float* gsum   = (float*)alloc((size_t)NG * H * 4);

  const int n2 = 2 * NN;                 // 100000 counters
  const int nb = (n2 + 1023) / 1024;     // 98 scan blocks

  // ---- one-time setup ----
  hipMemsetAsync(cursor, 0, n2 * 4, stream);
  hist_kernel<<<(2 * NE + 255) / 256, 256, 0, stream>>>(edges, cursor);
  scan1_kernel<<<nb, 1024, 0, stream>>>(cursor, rowptr, bsum, n2);
  scan2_kernel<<<1, 128, 0, stream>>>(bsum, boff, nb);
  scan3_kernel<<<(n2 + 255) / 256, 256, 0, stream>>>(rowptr, boff, n2);
  total_kernel<<<1, 64, 0, stream>>>(rowptr, boff, n2, nb);
  copy_int_kernel<<<(n2 + 255) / 256, 256, 0, stream>>>(rowptr, cursor, n2);
  fill_kernel<<<(2 * NE + 255) / 256, 256, 0, stream>>>(edges, cursor, colbuf);
  bounds_kernel<<<1, 128, 0, stream>>>(graph_ids, gstart);
  build_B_kernel<<<(VC * KB + 255) / 256, 256, 0, stream>>>(w_ih, w_hh, edge_W, Bh, Bl);
  build_coef_kernel<<<(VC + 255) / 256, 256, 0, stream>>>(w_ih, edge_b, b_ih, b_hh, coefs);
  init_nodes_kernel<<<(NN * 160 + 255) / 256, 256, 0, stream>>>(nodes_in, npkA, npkB);
  pad_S_kernel<<<(NN * 20 + 255) / 256, 256, 0, stream>>>(Sh, Sl);

  // ---- 5 message-passing iterations (packed nodes ping-pong) ----
  const int ngrp = (NRB + 7) / 8;        // 49 groups of 8 row-blocks
  u32* nbuf[2] = {npkA, npkB};
  for (int pass = 0; pass < NPASS; pass++) {
    u32* cur = nbuf[pass & 1];
    u32* nxt = nbuf[1 - (pass & 1)];
    gather_kernel<<<(NN * 64 + 255) / 256, 256, 0, stream>>>(cur, rowptr, colbuf, Sh, Sl);
    gru_gemm_kernel<<<ngrp * 5 * 8, 256, 0, stream>>>(
        Sh, Sl, cur, Bh, Bl, coefs, rowptr, nxt);
  }
  u32* fin = nbuf[NPASS & 1];

  // ---- readout ----
  hipMemsetAsync(gsum, 0, (size_t)NG * H * 4, stream);
  segsum_kernel<<<dim3(NG, 4), 192, 0, stream>>>(fin, gstart, gsum);
  head_kernel<<<NG, 192, 0, stream>>>(gsum, problem_type, fc1_w, fc1_b, fc2_w, fc2_b,
                                      fcL_w, fcL_b, (float*)d_out);
}